// Round 8
// baseline (172.392 us; speedup 1.0000x reference)
//
#include <hip/hip_runtime.h>
#include <math.h>

#define B_ 32
#define L_ 2048
#define D_ 512
#define K_ 512
#define CONC_ 100.0f
#define EPS_ 1e-12f
#define LSPLIT 16   // 16 chunks of 128 l's (= GEMM l-tile)

typedef __attribute__((ext_vector_type(8))) _Float16 f16x8;
typedef __attribute__((ext_vector_type(4))) _Float16 f16x4;
typedef __attribute__((ext_vector_type(4))) float f32x4;

// ---- workspace layout (float offsets) ----
enum : size_t {
  O_SCALE = 0,                          // B*D  (raw sum_l x^2, accumulated)
  O_INV   = O_SCALE + B_*D_,            // B*D  (1/max(scale/L,eps))
  O_MEANC = O_INV + B_*D_,              // D
  O_PM    = O_MEANC + D_,               // B*LSPLIT*K  (chunk max)
  O_PS    = O_PM + (size_t)B_*LSPLIT*K_,// B*LSPLIT*K  (chunk sum)
  O_WX    = O_PS + (size_t)B_*LSPLIT*K_,// B*D  (raw weighted-x accum)
  O_CF16  = O_WX + B_*D_,               // K*D halfs = 131072 floats
  O_L16   = O_CF16 + (size_t)K_*D_/2,   // B*L*K halfs (shifted logits)
  WS_FLOATS = O_L16 + (size_t)B_*L_*K_/2
};

__device__ __forceinline__ void gl2lds16(const void* gsrc, void* lds) {
  __builtin_amdgcn_global_load_lds(
      (const __attribute__((address_space(1))) void*)gsrc,
      (__attribute__((address_space(3))) void*)lds, 16, 0, 0);
}

// merged prep: centhalf (blocks 0..255), meanc (256..257),
// zero scale (258..321), zero wx (322..385)
__global__ void k_prep(const float* __restrict__ cent, float* ws) {
  int blk = blockIdx.x, tid = threadIdx.x;
  if (blk < 256) {
    int i = (blk * 256 + tid) * 4;
    float4 v = *reinterpret_cast<const float4*>(cent + i);
    f16x4 h;
    h[0] = (_Float16)(v.x * (2.f * CONC_));
    h[1] = (_Float16)(v.y * (2.f * CONC_));
    h[2] = (_Float16)(v.z * (2.f * CONC_));
    h[3] = (_Float16)(v.w * (2.f * CONC_));
    *reinterpret_cast<f16x4*>(reinterpret_cast<_Float16*>(ws + O_CF16) + i) = h;
  } else if (blk < 258) {
    int d = (blk - 256) * 256 + tid;
    float s = 0.f;
    for (int k = 0; k < K_; ++k) s += cent[(size_t)k * D_ + d];
    ws[O_MEANC + d] = s * (1.f / K_);
  } else if (blk < 322) {
    ws[O_SCALE + (blk - 258) * 256 + tid] = 0.f;
  } else {
    ws[O_WX + (blk - 322) * 256 + tid] = 0.f;
  }
}

// accumulate sum_l x^2 into scale (raw, not divided)
__global__ void k_sqacc(const float* __restrict__ x, float* ws) {
  int b = blockIdx.x, dc = blockIdx.y, lc = blockIdx.z;
  int d = dc * 256 + threadIdx.x;
  const float* xb = x + ((size_t)b * L_ + lc * 256) * D_ + d;
  float acc = 0.f;
  for (int l = 0; l < 256; ++l) {
    float v = xb[(size_t)l * D_];
    acc += v * v;
  }
  atomicAdd(&ws[O_SCALE + b * D_ + d], acc);
}

// inv = 1/max(scale/L, eps)
__global__ void k_finscale(float* ws) {
  int i = blockIdx.x * 256 + threadIdx.x;   // B*D = 16384
  ws[O_INV + i] = 1.f / fmaxf(ws[O_SCALE + i] * (1.f / L_), EPS_);
}

// MFMA GEMM + fused per-chunk softmax partials + fp16 shifted-logit store.
// 128x128 tile, BK=32, 4 waves (2x2), acc[4][4] -> ~3 waves/SIMD occupancy.
// A reg-staged from x fp32 (*inv, cvt f16, swizzled ds_write); B via
// global_load_lds with pre-swizzled source. Single-buffered (r2/r4-proven).
__global__ __launch_bounds__(256) void k_gemm16(const float* __restrict__ x,
                                                float* ws) {
  const int b = blockIdx.z;
  const int l0 = blockIdx.x * 128;
  const int k0 = blockIdx.y * 128;
  __shared__ _Float16 As[128 * 32];   // 8 KB
  __shared__ _Float16 Bs[128 * 32];   // 8 KB
  const int tid = threadIdx.x;
  const int lane = tid & 63;
  const int w = tid >> 6;
  const int wm = w >> 1, wn = w & 1;

  const _Float16* cf = reinterpret_cast<const _Float16*>(ws + O_CF16);
  const float* xb = x + (size_t)b * L_ * D_;
  const float* invb = ws + O_INV + b * D_;

  f32x4 acc[4][4] = {};

  for (int d0 = 0; d0 < D_; d0 += 32) {
    // stage B (cent16) via global_load_lds, source pre-swizzled
#pragma unroll
    for (int r = 0; r < 2; ++r) {
      int u = r * 256 + tid;               // 16B unit 0..511
      int row = u >> 2, slot = u & 3;
      int sc = (slot ^ ((row >> 1) & 3)) * 8;
      gl2lds16(cf + (size_t)(k0 + row) * D_ + d0 + sc, Bs + (size_t)u * 8);
    }
    // stage A: x fp32 -> *inv -> f16, swizzled ds_write
#pragma unroll
    for (int r = 0; r < 4; ++r) {
      int f = r * 256 + tid;               // 8B unit 0..1023
      int row = f >> 3;                    // l row 0..127
      int col4 = (f & 7) << 2;             // 0,4,..,28
      float4 xv = *reinterpret_cast<const float4*>(
          xb + (size_t)(l0 + row) * D_ + d0 + col4);
      float4 iv = *reinterpret_cast<const float4*>(invb + d0 + col4);
      f16x4 hv;
      hv[0] = (_Float16)(xv.x * iv.x);
      hv[1] = (_Float16)(xv.y * iv.y);
      hv[2] = (_Float16)(xv.z * iv.z);
      hv[3] = (_Float16)(xv.w * iv.w);
      int slot = col4 >> 3;
      int half = (col4 >> 2) & 1;
      int sw = slot ^ ((row >> 1) & 3);
      *reinterpret_cast<f16x4*>(
          reinterpret_cast<char*>(As) + row * 64 + sw * 16 + half * 8) = hv;
    }
    __syncthreads();

    f16x8 af[4], bfr[4];
#pragma unroll
    for (int mi = 0; mi < 4; ++mi) {
      int row = wm * 64 + mi * 16 + (lane & 15);
      int sw = (lane >> 4) ^ ((row >> 1) & 3);
      af[mi] = *reinterpret_cast<const f16x8*>(
          reinterpret_cast<const char*>(As) + row * 64 + sw * 16);
    }
#pragma unroll
    for (int ni = 0; ni < 4; ++ni) {
      int row = wn * 64 + ni * 16 + (lane & 15);
      int sw = (lane >> 4) ^ ((row >> 1) & 3);
      bfr[ni] = *reinterpret_cast<const f16x8*>(
          reinterpret_cast<const char*>(Bs) + row * 64 + sw * 16);
    }
#pragma unroll
    for (int mi = 0; mi < 4; ++mi)
#pragma unroll
      for (int ni = 0; ni < 4; ++ni)
        acc[mi][ni] = __builtin_amdgcn_mfma_f32_16x16x32_f16(
            af[mi], bfr[ni], acc[mi][ni], 0, 0, 0);
    __syncthreads();
  }

  // ---- fused softmax partials over this block's 128 l's ----
  // (bias[k] omitted: constant over l, cancels in softmax over l)
  float* red = reinterpret_cast<float*>(As);   // [2 wm][128 k] wave maxes
  float* red2 = red + 256;                     // [2 wm][128 k] wave sums
  float pm[4], ps[4];
#pragma unroll
  for (int ni = 0; ni < 4; ++ni) {
    float m = -INFINITY;
#pragma unroll
    for (int mi = 0; mi < 4; ++mi)
#pragma unroll
      for (int j = 0; j < 4; ++j) m = fmaxf(m, acc[mi][ni][j]);
    m = fmaxf(m, __shfl_xor(m, 16));
    m = fmaxf(m, __shfl_xor(m, 32));
    pm[ni] = m;
  }
  if (lane < 16) {
#pragma unroll
    for (int ni = 0; ni < 4; ++ni)
      red[wm * 128 + wn * 64 + ni * 16 + lane] = pm[ni];
  }
  __syncthreads();
#pragma unroll
  for (int ni = 0; ni < 4; ++ni) {
    int idx = wn * 64 + ni * 16 + (lane & 15);
    pm[ni] = fmaxf(red[idx], red[128 + idx]);   // combined chunk max
  }
#pragma unroll
  for (int ni = 0; ni < 4; ++ni) {
    float s = 0.f;
#pragma unroll
    for (int mi = 0; mi < 4; ++mi)
#pragma unroll
      for (int j = 0; j < 4; ++j) s += expf(acc[mi][ni][j] - pm[ni]);
    s += __shfl_xor(s, 16);
    s += __shfl_xor(s, 32);
    ps[ni] = s;
  }
  if (lane < 16) {
#pragma unroll
    for (int ni = 0; ni < 4; ++ni)
      red2[wm * 128 + wn * 64 + ni * 16 + lane] = ps[ni];
  }
  __syncthreads();
  if (w < 2 && lane < 16) {
#pragma unroll
    for (int ni = 0; ni < 4; ++ni) {
      int idx = wn * 64 + ni * 16 + lane;
      float mg = fmaxf(red[idx], red[128 + idx]);
      float sg = red2[idx] + red2[128 + idx];
      size_t o = ((size_t)b * LSPLIT + blockIdx.x) * K_ + k0 + idx;
      ws[O_PM + o] = mg;
      ws[O_PS + o] = sg;
    }
  }
  // store fp16 shifted logits (v - chunk_max), linear [b][l][k]
  _Float16* lg = reinterpret_cast<_Float16*>(ws + O_L16) + (size_t)b * L_ * K_;
#pragma unroll
  for (int ni = 0; ni < 4; ++ni) {
    int kc = k0 + wn * 64 + ni * 16 + (lane & 15);
#pragma unroll
    for (int mi = 0; mi < 4; ++mi) {
      int lr = l0 + wm * 64 + mi * 16 + (lane >> 4) * 4;
#pragma unroll
      for (int j = 0; j < 4; ++j)
        lg[(size_t)(lr + j) * K_ + kc] = (_Float16)(acc[mi][ni][j] - pm[ni]);
    }
  }
}

// fused: recompute chunk->global combine (read-only PM/PS), then
// w[l] = sum_k exp(vshift[l,k])*A[k]; then wx[b,d] += sum_l w[l]*x[b,l,d]
// (inv factors out of the weighted sum; applied in k_final)
__global__ __launch_bounds__(256) void k_wsumwx(const float* __restrict__ x,
                                                float* ws) {
  int b = blockIdx.x, ch = blockIdx.y;
  int l0 = ch * 128;
  __shared__ float wl[128];
  __shared__ float Al[512];
  int tid = threadIdx.x, lane = tid & 63, wv = tid >> 6;

  // combine: A[k] = exp(pm[ch,k] - M[k]) / S[k]
  for (int kk = tid; kk < K_; kk += 256) {
    float pmv[LSPLIT], psv[LSPLIT];
    float M = -INFINITY;
#pragma unroll
    for (int c = 0; c < LSPLIT; ++c) {
      pmv[c] = ws[O_PM + ((size_t)b * LSPLIT + c) * K_ + kk];
      psv[c] = ws[O_PS + ((size_t)b * LSPLIT + c) * K_ + kk];
      M = fmaxf(M, pmv[c]);
    }
    float S = 0.f;
#pragma unroll
    for (int c = 0; c < LSPLIT; ++c) S += psv[c] * expf(pmv[c] - M);
    Al[kk] = expf(pmv[ch] - M) / S;
  }
  __syncthreads();

  const _Float16* lg = reinterpret_cast<const _Float16*>(ws + O_L16) +
                       (size_t)(b * L_ + l0) * K_;
  float a8[8];
#pragma unroll
  for (int i = 0; i < 8; ++i) a8[i] = Al[lane * 8 + i];

  for (int il = 0; il < 32; ++il) {
    int ll = wv * 32 + il;
    f16x8 v = *reinterpret_cast<const f16x8*>(lg + (size_t)ll * K_ + lane * 8);
    float s = 0.f;
#pragma unroll
    for (int i = 0; i < 8; ++i) s += expf((float)v[i]) * a8[i];
#pragma unroll
    for (int off = 32; off > 0; off >>= 1) s += __shfl_xor(s, off);
    if (lane == 0) wl[ll] = s;
  }
  __syncthreads();

  const float* xb = x + (size_t)(b * L_ + l0) * D_;
  int half = tid >> 7;            // 0/1 -> l 0..63 / 64..127
  int dd = (tid & 127) * 4;
  float4 a4 = {0.f, 0.f, 0.f, 0.f};
  for (int l = half * 64; l < half * 64 + 64; ++l) {
    float wgt = wl[l];
    float4 xv = *reinterpret_cast<const float4*>(xb + (size_t)l * D_ + dd);
    a4.x += wgt * xv.x;
    a4.y += wgt * xv.y;
    a4.z += wgt * xv.z;
    a4.w += wgt * xv.w;
  }
  atomicAdd(&ws[O_WX + b * D_ + dd + 0], a4.x);
  atomicAdd(&ws[O_WX + b * D_ + dd + 1], a4.y);
  atomicAdd(&ws[O_WX + b * D_ + dd + 2], a4.z);
  atomicAdd(&ws[O_WX + b * D_ + dd + 3], a4.w);
}

// out[b,d] = (rawscale/L) * (inv*wx/K - meanC[d])
__global__ void k_final(const float* ws, float* out) {
  int i = blockIdx.x * 256 + threadIdx.x;
  int d = i & (D_ - 1);
  out[i] = (ws[O_SCALE + i] * (1.f / L_)) *
           (ws[O_INV + i] * ws[O_WX + i] * (1.f / K_) - ws[O_MEANC + d]);
}

extern "C" void kernel_launch(void* const* d_in, const int* in_sizes, int n_in,
                              void* d_out, int out_size, void* d_ws, size_t ws_size,
                              hipStream_t stream) {
  const float* x = (const float*)d_in[0];
  const float* cent = (const float*)d_in[1];
  float* out = (float*)d_out;
  float* ws = (float*)d_ws;

  k_prep<<<386, 256, 0, stream>>>(cent, ws);
  k_sqacc<<<dim3(B_, D_ / 256, 8), 256, 0, stream>>>(x, ws);
  k_finscale<<<B_ * D_ / 256, 256, 0, stream>>>(ws);
  k_gemm16<<<dim3(L_ / 128, K_ / 128, B_), 256, 0, stream>>>(x, ws);
  k_wsumwx<<<dim3(B_, LSPLIT), 256, 0, stream>>>(x, ws);
  k_final<<<B_ * D_ / 256, 256, 0, stream>>>(ws, out);
}

// Round 9
// 172.327 us; speedup vs baseline: 1.0004x; 1.0004x over previous
//
#include <hip/hip_runtime.h>
#include <math.h>

#define B_ 32
#define L_ 2048
#define D_ 512
#define K_ 512
#define CONC_ 100.0f
#define EPS_ 1e-12f
#define LSPLIT 16   // 16 chunks of 128 l's (= GEMM l-tile)

typedef __attribute__((ext_vector_type(8))) _Float16 f16x8;
typedef __attribute__((ext_vector_type(4))) _Float16 f16x4;
typedef __attribute__((ext_vector_type(4))) float f32x4;

// ---- workspace layout (float offsets) ----
enum : size_t {
  O_SCALE = 0,                            // B*D  raw sum_l x^2
  O_MEANC = O_SCALE + B_*D_,              // D
  O_PM    = O_MEANC + D_,                 // B*LSPLIT*K  chunk max
  O_PS    = O_PM + (size_t)B_*LSPLIT*K_,  // B*LSPLIT*K  chunk sum
  O_WX    = O_PS + (size_t)B_*LSPLIT*K_,  // B*D
  O_CFB   = O_WX + B_*D_,                 // B*K*D halfs (200*cent*inv)
  O_X16   = O_CFB + (size_t)B_*K_*D_/2,   // B*L*D halfs (fp16 x, no inv)
  O_P16   = O_X16 + (size_t)B_*L_*D_/2,   // B*L*K halfs (exp(v-m_chunk))
  WS_FLOATS = O_P16 + (size_t)B_*L_*K_/2  // ~153 MB
};

__device__ __forceinline__ void gl2lds16(const void* gsrc, void* lds) {
  __builtin_amdgcn_global_load_lds(
      (const __attribute__((address_space(1))) void*)gsrc,
      (__attribute__((address_space(3))) void*)lds, 16, 0, 0);
}

// prep: meanc (blk 0..1), zero scale (2..65), zero wx (66..129)
__global__ void k_prep(const float* __restrict__ cent, float* ws) {
  int blk = blockIdx.x, tid = threadIdx.x;
  if (blk < 2) {
    int d = blk * 256 + tid;
    float s = 0.f;
    for (int k = 0; k < K_; ++k) s += cent[(size_t)k * D_ + d];
    ws[O_MEANC + d] = s * (1.f / K_);
  } else if (blk < 66) {
    ws[O_SCALE + (blk - 2) * 256 + tid] = 0.f;
  } else {
    ws[O_WX + (blk - 66) * 256 + tid] = 0.f;
  }
}

// accumulate sum_l x^2 into scale AND emit x16 = fp16(x) (raw, no inv)
__global__ void k_sqacc(const float* __restrict__ x, float* ws) {
  int b = blockIdx.x, dc = blockIdx.y, lc = blockIdx.z;
  int d = dc * 256 + threadIdx.x;
  size_t base = ((size_t)b * L_ + lc * 256) * D_ + d;
  const float* xb = x + base;
  _Float16* x16b = reinterpret_cast<_Float16*>(ws + O_X16) + base;
  float acc = 0.f;
  for (int l = 0; l < 256; ++l) {
    float v = xb[(size_t)l * D_];
    acc += v * v;
    x16b[(size_t)l * D_] = (_Float16)v;
  }
  atomicAdd(&ws[O_SCALE + b * D_ + d], acc);
}

// cfb16[b,k,d] = fp16(200 * cent[k,d] / max(scale[b,d]/L, eps))
__global__ void k_cfb(const float* __restrict__ cent, float* ws) {
  int b = blockIdx.y;
  int f = (blockIdx.x * 256 + threadIdx.x) * 4;   // flat [k][d] index
  int d = f & (D_ - 1);
  float4 c = *reinterpret_cast<const float4*>(cent + f);
  float4 s4 = *reinterpret_cast<const float4*>(ws + O_SCALE + (size_t)b * D_ + d);
  f16x4 h;
  h[0] = (_Float16)(c.x * (2.f * CONC_) / fmaxf(s4.x * (1.f / L_), EPS_));
  h[1] = (_Float16)(c.y * (2.f * CONC_) / fmaxf(s4.y * (1.f / L_), EPS_));
  h[2] = (_Float16)(c.z * (2.f * CONC_) / fmaxf(s4.z * (1.f / L_), EPS_));
  h[3] = (_Float16)(c.w * (2.f * CONC_) / fmaxf(s4.w * (1.f / L_), EPS_));
  *reinterpret_cast<f16x4*>(
      reinterpret_cast<_Float16*>(ws + O_CFB) + (size_t)b * K_ * D_ + f) = h;
}

// MFMA GEMM: logits[l,k] = sum_d x16[l,d]*cfb16[k,d]. Both operands staged
// via global_load_lds (pre-swizzled source, zero staging VALU — r4-proven).
// 128x128 tile, BK=32, 4 waves (2x2), acc[4][4]. Fused epilogue: per-chunk
// softmax partials + P16 = exp(v - chunk_max) store (exp computed for the
// sum anyway — the separate logit-store pass is gone).
__global__ __launch_bounds__(256) void k_gemm16(float* ws) {
  const int b = blockIdx.z;
  const int l0 = blockIdx.x * 128;
  const int k0 = blockIdx.y * 128;
  __shared__ _Float16 As[128 * 32];   // 8 KB
  __shared__ _Float16 Bs[128 * 32];   // 8 KB
  const int tid = threadIdx.x;
  const int lane = tid & 63;
  const int w = tid >> 6;
  const int wm = w >> 1, wn = w & 1;

  const _Float16* xb16 = reinterpret_cast<const _Float16*>(ws + O_X16) +
                         (size_t)b * L_ * D_;
  const _Float16* cfb = reinterpret_cast<const _Float16*>(ws + O_CFB) +
                        (size_t)b * K_ * D_;

  f32x4 acc[4][4] = {};

  for (int d0 = 0; d0 < D_; d0 += 32) {
#pragma unroll
    for (int r = 0; r < 2; ++r) {
      int u = r * 256 + tid;               // 16B unit 0..511
      int row = u >> 2, slot = u & 3;
      int sc = (slot ^ ((row >> 1) & 3)) * 8;
      gl2lds16(xb16 + (size_t)(l0 + row) * D_ + d0 + sc, As + (size_t)u * 8);
    }
#pragma unroll
    for (int r = 0; r < 2; ++r) {
      int u = r * 256 + tid;
      int row = u >> 2, slot = u & 3;
      int sc = (slot ^ ((row >> 1) & 3)) * 8;
      gl2lds16(cfb + (size_t)(k0 + row) * D_ + d0 + sc, Bs + (size_t)u * 8);
    }
    __syncthreads();

    f16x8 af[4], bfr[4];
#pragma unroll
    for (int mi = 0; mi < 4; ++mi) {
      int row = wm * 64 + mi * 16 + (lane & 15);
      int sw = (lane >> 4) ^ ((row >> 1) & 3);
      af[mi] = *reinterpret_cast<const f16x8*>(
          reinterpret_cast<const char*>(As) + row * 64 + sw * 16);
    }
#pragma unroll
    for (int ni = 0; ni < 4; ++ni) {
      int row = wn * 64 + ni * 16 + (lane & 15);
      int sw = (lane >> 4) ^ ((row >> 1) & 3);
      bfr[ni] = *reinterpret_cast<const f16x8*>(
          reinterpret_cast<const char*>(Bs) + row * 64 + sw * 16);
    }
#pragma unroll
    for (int mi = 0; mi < 4; ++mi)
#pragma unroll
      for (int ni = 0; ni < 4; ++ni)
        acc[mi][ni] = __builtin_amdgcn_mfma_f32_16x16x32_f16(
            af[mi], bfr[ni], acc[mi][ni], 0, 0, 0);
    __syncthreads();
  }

  // ---- fused softmax partials over this block's 128 l's ----
  // (bias[k] omitted: constant over l, cancels in softmax over l)
  float* red = reinterpret_cast<float*>(As);   // [2 wm][128 k] wave maxes
  float* red2 = red + 256;                     // [2 wm][128 k] wave sums
  float pm[4], ps[4];
#pragma unroll
  for (int ni = 0; ni < 4; ++ni) {
    float m = -INFINITY;
#pragma unroll
    for (int mi = 0; mi < 4; ++mi)
#pragma unroll
      for (int j = 0; j < 4; ++j) m = fmaxf(m, acc[mi][ni][j]);
    m = fmaxf(m, __shfl_xor(m, 16));
    m = fmaxf(m, __shfl_xor(m, 32));
    pm[ni] = m;
  }
  if (lane < 16) {
#pragma unroll
    for (int ni = 0; ni < 4; ++ni)
      red[wm * 128 + wn * 64 + ni * 16 + lane] = pm[ni];
  }
  __syncthreads();
#pragma unroll
  for (int ni = 0; ni < 4; ++ni) {
    int idx = wn * 64 + ni * 16 + (lane & 15);
    pm[ni] = fmaxf(red[idx], red[128 + idx]);   // combined chunk max
  }
  // single pass: e = exp(v - m_chunk); accumulate sum AND store P16
  _Float16* pg = reinterpret_cast<_Float16*>(ws + O_P16) + (size_t)b * L_ * K_;
#pragma unroll
  for (int ni = 0; ni < 4; ++ni) {
    int kc = k0 + wn * 64 + ni * 16 + (lane & 15);
    float s = 0.f;
#pragma unroll
    for (int mi = 0; mi < 4; ++mi) {
      int lr = l0 + wm * 64 + mi * 16 + (lane >> 4) * 4;
#pragma unroll
      for (int j = 0; j < 4; ++j) {
        float e = expf(acc[mi][ni][j] - pm[ni]);
        s += e;
        pg[(size_t)(lr + j) * K_ + kc] = (_Float16)e;
      }
    }
    s += __shfl_xor(s, 16);
    s += __shfl_xor(s, 32);
    ps[ni] = s;
  }
  if (lane < 16) {
#pragma unroll
    for (int ni = 0; ni < 4; ++ni)
      red2[wm * 128 + wn * 64 + ni * 16 + lane] = ps[ni];
  }
  __syncthreads();
  if (w < 2 && lane < 16) {
#pragma unroll
    for (int ni = 0; ni < 4; ++ni) {
      int idx = wn * 64 + ni * 16 + lane;
      float mg = fmaxf(red[idx], red[128 + idx]);
      float sg = red2[idx] + red2[128 + idx];
      size_t o = ((size_t)b * LSPLIT + blockIdx.x) * K_ + k0 + idx;
      ws[O_PM + o] = mg;
      ws[O_PS + o] = sg;
    }
  }
}

// fused: combine chunk stats -> A[k]; w[l] = sum_k P16[l,k]*A[k] (no expf);
// wx[b,d] += sum_l w[l]*x16[l,d]  (inv applied in k_final)
__global__ __launch_bounds__(256) void k_wsumwx(float* ws) {
  int b = blockIdx.x, ch = blockIdx.y;
  int l0 = ch * 128;
  __shared__ float wl[128];
  __shared__ float Al[512];
  int tid = threadIdx.x, lane = tid & 63, wv = tid >> 6;

  // combine: A[k] = exp(pm[ch,k] - M[k]) / S[k]
  for (int kk = tid; kk < K_; kk += 256) {
    float pmv[LSPLIT], psv[LSPLIT];
    float M = -INFINITY;
#pragma unroll
    for (int c = 0; c < LSPLIT; ++c) {
      pmv[c] = ws[O_PM + ((size_t)b * LSPLIT + c) * K_ + kk];
      psv[c] = ws[O_PS + ((size_t)b * LSPLIT + c) * K_ + kk];
      M = fmaxf(M, pmv[c]);
    }
    float S = 0.f;
#pragma unroll
    for (int c = 0; c < LSPLIT; ++c) S += psv[c] * expf(pmv[c] - M);
    Al[kk] = expf(pmv[ch] - M) / S;
  }
  __syncthreads();

  const _Float16* pg = reinterpret_cast<const _Float16*>(ws + O_P16) +
                       (size_t)(b * L_ + l0) * K_;
  float a8[8];
#pragma unroll
  for (int i = 0; i < 8; ++i) a8[i] = Al[lane * 8 + i];

  for (int il = 0; il < 32; ++il) {
    int ll = wv * 32 + il;
    f16x8 v = *reinterpret_cast<const f16x8*>(pg + (size_t)ll * K_ + lane * 8);
    float s = 0.f;
#pragma unroll
    for (int i = 0; i < 8; ++i) s += (float)v[i] * a8[i];
#pragma unroll
    for (int off = 32; off > 0; off >>= 1) s += __shfl_xor(s, off);
    if (lane == 0) wl[ll] = s;
  }
  __syncthreads();

  const _Float16* x16b = reinterpret_cast<const _Float16*>(ws + O_X16) +
                         (size_t)(b * L_ + l0) * D_;
  int half = tid >> 7;            // 0/1 -> l 0..63 / 64..127
  int dd = (tid & 127) * 4;
  float4 a4 = {0.f, 0.f, 0.f, 0.f};
  for (int l = half * 64; l < half * 64 + 64; ++l) {
    float wgt = wl[l];
    f16x4 xv = *reinterpret_cast<const f16x4*>(x16b + (size_t)l * D_ + dd);
    a4.x += wgt * (float)xv[0];
    a4.y += wgt * (float)xv[1];
    a4.z += wgt * (float)xv[2];
    a4.w += wgt * (float)xv[3];
  }
  atomicAdd(&ws[O_WX + b * D_ + dd + 0], a4.x);
  atomicAdd(&ws[O_WX + b * D_ + dd + 1], a4.y);
  atomicAdd(&ws[O_WX + b * D_ + dd + 2], a4.z);
  atomicAdd(&ws[O_WX + b * D_ + dd + 3], a4.w);
}

// out[b,d] = (scale/L) * (inv*wx/K - meanC[d]),  inv = 1/max(scale/L, eps)
__global__ void k_final(const float* ws, float* out) {
  int i = blockIdx.x * 256 + threadIdx.x;
  int d = i & (D_ - 1);
  float sc = ws[O_SCALE + i] * (1.f / L_);
  float inv = 1.f / fmaxf(sc, EPS_);
  out[i] = sc * (inv * ws[O_WX + i] * (1.f / K_) - ws[O_MEANC + d]);
}

extern "C" void kernel_launch(void* const* d_in, const int* in_sizes, int n_in,
                              void* d_out, int out_size, void* d_ws, size_t ws_size,
                              hipStream_t stream) {
  const float* x = (const float*)d_in[0];
  const float* cent = (const float*)d_in[1];
  float* out = (float*)d_out;
  float* ws = (float*)d_ws;

  k_prep<<<130, 256, 0, stream>>>(cent, ws);
  k_sqacc<<<dim3(B_, D_ / 256, 8), 256, 0, stream>>>(x, ws);
  k_cfb<<<dim3(K_ * D_ / 1024, B_), 256, 0, stream>>>(cent, ws);
  k_gemm16<<<dim3(L_ / 128, K_ / 128, B_), 256, 0, stream>>>(ws);
  k_wsumwx<<<dim3(B_, LSPLIT), 256, 0, stream>>>(ws);
  k_final<<<B_ * D_ / 256, 256, 0, stream>>>(ws, out);
}

// Round 10
// 165.940 us; speedup vs baseline: 1.0389x; 1.0385x over previous
//
#include <hip/hip_runtime.h>
#include <math.h>

#define B_ 32
#define L_ 2048
#define D_ 512
#define K_ 512
#define CONC_ 100.0f
#define EPS_ 1e-12f
#define LSPLIT 16   // 16 chunks of 128 l's (= GEMM l-tile)

typedef __attribute__((ext_vector_type(8))) _Float16 f16x8;
typedef __attribute__((ext_vector_type(4))) _Float16 f16x4;
typedef __attribute__((ext_vector_type(4))) float f32x4;

// ---- workspace layout (float offsets) ----
enum : size_t {
  O_SCALE = 0,                            // B*D  raw sum_l x^2
  O_MEANC = O_SCALE + B_*D_,              // D
  O_PM    = O_MEANC + D_,                 // B*LSPLIT*K  chunk max
  O_PS    = O_PM + (size_t)B_*LSPLIT*K_,  // B*LSPLIT*K  chunk sum
  O_WX    = O_PS + (size_t)B_*LSPLIT*K_,  // B*D
  O_CFB   = O_WX + B_*D_,                 // B*K*D halfs (200*cent*inv)
  O_X16   = O_CFB + (size_t)B_*K_*D_/2,   // B*L*D halfs (fp16 x, no inv)
  O_P16   = O_X16 + (size_t)B_*L_*D_/2,   // B*K*L halfs TRANSPOSED exp(v-m)
  WS_FLOATS = O_P16 + (size_t)B_*L_*K_/2  // ~153 MB
};

__device__ __forceinline__ void gl2lds16(const void* gsrc, void* lds) {
  __builtin_amdgcn_global_load_lds(
      (const __attribute__((address_space(1))) void*)gsrc,
      (__attribute__((address_space(3))) void*)lds, 16, 0, 0);
}

// prep: meanc (blk 0..1), zero scale (2..65), zero wx (66..129)
__global__ void k_prep(const float* __restrict__ cent, float* ws) {
  int blk = blockIdx.x, tid = threadIdx.x;
  if (blk < 2) {
    int d = blk * 256 + tid;
    float s = 0.f;
    for (int k = 0; k < K_; ++k) s += cent[(size_t)k * D_ + d];
    ws[O_MEANC + d] = s * (1.f / K_);
  } else if (blk < 66) {
    ws[O_SCALE + (blk - 2) * 256 + tid] = 0.f;
  } else {
    ws[O_WX + (blk - 66) * 256 + tid] = 0.f;
  }
}

// accumulate sum_l x^2 into scale AND emit x16 = fp16(x) (raw, no inv)
__global__ void k_sqacc(const float* __restrict__ x, float* ws) {
  int b = blockIdx.x, dc = blockIdx.y, lc = blockIdx.z;
  int d = dc * 256 + threadIdx.x;
  size_t base = ((size_t)b * L_ + lc * 256) * D_ + d;
  const float* xb = x + base;
  _Float16* x16b = reinterpret_cast<_Float16*>(ws + O_X16) + base;
  float acc = 0.f;
  for (int l = 0; l < 256; ++l) {
    float v = xb[(size_t)l * D_];
    acc += v * v;
    x16b[(size_t)l * D_] = (_Float16)v;
  }
  atomicAdd(&ws[O_SCALE + b * D_ + d], acc);
}

// cfb16[b,k,d] = fp16(200 * cent[k,d] / max(scale[b,d]/L, eps))
__global__ void k_cfb(const float* __restrict__ cent, float* ws) {
  int b = blockIdx.y;
  int f = (blockIdx.x * 256 + threadIdx.x) * 4;   // flat [k][d] index
  int d = f & (D_ - 1);
  float4 c = *reinterpret_cast<const float4*>(cent + f);
  float4 s4 = *reinterpret_cast<const float4*>(ws + O_SCALE + (size_t)b * D_ + d);
  f16x4 h;
  h[0] = (_Float16)(c.x * (2.f * CONC_) / fmaxf(s4.x * (1.f / L_), EPS_));
  h[1] = (_Float16)(c.y * (2.f * CONC_) / fmaxf(s4.y * (1.f / L_), EPS_));
  h[2] = (_Float16)(c.z * (2.f * CONC_) / fmaxf(s4.z * (1.f / L_), EPS_));
  h[3] = (_Float16)(c.w * (2.f * CONC_) / fmaxf(s4.w * (1.f / L_), EPS_));
  *reinterpret_cast<f16x4*>(
      reinterpret_cast<_Float16*>(ws + O_CFB) + (size_t)b * K_ * D_ + f) = h;
}

// MFMA GEMM with T4 counted-vmcnt double-buffered pipeline.
// 128x128 tile, BK=32, 4 waves (2x2), acc[4][4]. Per iter:
//   barrier1 (prev reads done) -> STAGE(next buf) -> vmcnt(4) -> barrier2
//   -> ds_read + 16 MFMA.  No vmcnt(0) drain in the loop.
// Fused epilogue: per-chunk softmax partials + P16 stored TRANSPOSED [k][l].
__global__ __launch_bounds__(256) void k_gemm16(float* ws) {
  const int b = blockIdx.z;
  const int l0 = blockIdx.x * 128;
  const int k0 = blockIdx.y * 128;
  __shared__ _Float16 As[2][128 * 32];   // 2 x 8 KB
  __shared__ _Float16 Bs[2][128 * 32];   // 2 x 8 KB
  const int tid = threadIdx.x;
  const int lane = tid & 63;
  const int w = tid >> 6;
  const int wm = w >> 1, wn = w & 1;

  const _Float16* xb16 = reinterpret_cast<const _Float16*>(ws + O_X16) +
                         (size_t)b * L_ * D_;
  const _Float16* cfb = reinterpret_cast<const _Float16*>(ws + O_CFB) +
                        (size_t)b * K_ * D_;

  const int u0 = tid;            // 16B unit 0..255
  const int u1 = 256 + tid;      // 16B unit 256..511
  const int row0 = u0 >> 2, sc0 = ((u0 & 3) ^ ((row0 >> 1) & 3)) * 8;
  const int row1 = u1 >> 2, sc1 = ((u1 & 3) ^ ((row1 >> 1) & 3)) * 8;

  f32x4 acc[4][4] = {};

#define STAGE(buf, d0)                                                         \
  {                                                                            \
    gl2lds16(xb16 + (size_t)(l0 + row0) * D_ + (d0) + sc0, &As[buf][u0 * 8]);  \
    gl2lds16(xb16 + (size_t)(l0 + row1) * D_ + (d0) + sc1, &As[buf][u1 * 8]);  \
    gl2lds16(cfb + (size_t)(k0 + row0) * D_ + (d0) + sc0, &Bs[buf][u0 * 8]);   \
    gl2lds16(cfb + (size_t)(k0 + row1) * D_ + (d0) + sc1, &Bs[buf][u1 * 8]);   \
  }

#define COMPUTE(cb)                                                            \
  {                                                                            \
    const char* Ac = reinterpret_cast<const char*>(As[cb]);                    \
    const char* Bc = reinterpret_cast<const char*>(Bs[cb]);                    \
    f16x8 af[4], bfr[4];                                                       \
    _Pragma("unroll") for (int mi = 0; mi < 4; ++mi) {                         \
      int row = wm * 64 + mi * 16 + (lane & 15);                               \
      int sw = (lane >> 4) ^ ((row >> 1) & 3);                                 \
      af[mi] = *reinterpret_cast<const f16x8*>(Ac + row * 64 + sw * 16);       \
    }                                                                          \
    _Pragma("unroll") for (int ni = 0; ni < 4; ++ni) {                         \
      int row = wn * 64 + ni * 16 + (lane & 15);                               \
      int sw = (lane >> 4) ^ ((row >> 1) & 3);                                 \
      bfr[ni] = *reinterpret_cast<const f16x8*>(Bc + row * 64 + sw * 16);      \
    }                                                                          \
    _Pragma("unroll") for (int mi = 0; mi < 4; ++mi)                           \
      _Pragma("unroll") for (int ni = 0; ni < 4; ++ni)                         \
        acc[mi][ni] = __builtin_amdgcn_mfma_f32_16x16x32_f16(                  \
            af[mi], bfr[ni], acc[mi][ni], 0, 0, 0);                            \
  }

  STAGE(0, 0);
  int cur = 0;
  for (int t = 0; t < 15; ++t) {
    __builtin_amdgcn_s_barrier();              // prev reads of buf[cur^1] done
    STAGE(cur ^ 1, (t + 1) * 32);              // prefetch next K-step
    asm volatile("s_waitcnt vmcnt(4)" ::: "memory");  // own cur-loads done
    __builtin_amdgcn_s_barrier();              // all waves' cur-loads done
    COMPUTE(cur);
    cur ^= 1;
  }
  asm volatile("s_waitcnt vmcnt(0)" ::: "memory");
  __builtin_amdgcn_s_barrier();
  COMPUTE(cur);
#undef STAGE
#undef COMPUTE
  __syncthreads();   // all reads done before As is reused as scratch

  // ---- fused softmax partials over this block's 128 l's ----
  // (bias[k] omitted: constant over l, cancels in softmax over l)
  float* red = reinterpret_cast<float*>(As);   // [2 wm][128 k] wave maxes
  float* red2 = red + 256;                     // [2 wm][128 k] wave sums
  float pm[4], ps[4];
#pragma unroll
  for (int ni = 0; ni < 4; ++ni) {
    float m = -INFINITY;
#pragma unroll
    for (int mi = 0; mi < 4; ++mi)
#pragma unroll
      for (int j = 0; j < 4; ++j) m = fmaxf(m, acc[mi][ni][j]);
    m = fmaxf(m, __shfl_xor(m, 16));
    m = fmaxf(m, __shfl_xor(m, 32));
    pm[ni] = m;
  }
  if (lane < 16) {
#pragma unroll
    for (int ni = 0; ni < 4; ++ni)
      red[wm * 128 + wn * 64 + ni * 16 + lane] = pm[ni];
  }
  __syncthreads();
#pragma unroll
  for (int ni = 0; ni < 4; ++ni) {
    int idx = wn * 64 + ni * 16 + (lane & 15);
    pm[ni] = fmaxf(red[idx], red[128 + idx]);   // combined chunk max
  }
  // single pass: e = exp(v - m_chunk); accumulate sum AND store P16
  // TRANSPOSED [b][k][l]: per (ni,mi) one 8B f16x4 store, l-contiguous.
  _Float16* pg = reinterpret_cast<_Float16*>(ws + O_P16) + (size_t)b * K_ * L_;
#pragma unroll
  for (int ni = 0; ni < 4; ++ni) {
    int kc = k0 + wn * 64 + ni * 16 + (lane & 15);
    float s = 0.f;
#pragma unroll
    for (int mi = 0; mi < 4; ++mi) {
      int lr = l0 + wm * 64 + mi * 16 + (lane >> 4) * 4;
      f16x4 ev;
#pragma unroll
      for (int j = 0; j < 4; ++j) {
        float e = expf(acc[mi][ni][j] - pm[ni]);
        s += e;
        ev[j] = (_Float16)e;
      }
      *reinterpret_cast<f16x4*>(pg + (size_t)kc * L_ + lr) = ev;
    }
    s += __shfl_xor(s, 16);
    s += __shfl_xor(s, 32);
    ps[ni] = s;
  }
  if (lane < 16) {
#pragma unroll
    for (int ni = 0; ni < 4; ++ni)
      red2[wm * 128 + wn * 64 + ni * 16 + lane] = ps[ni];
  }
  __syncthreads();
  if (w < 2 && lane < 16) {
#pragma unroll
    for (int ni = 0; ni < 4; ++ni) {
      int idx = wn * 64 + ni * 16 + lane;
      float mg = fmaxf(red[idx], red[128 + idx]);
      float sg = red2[idx] + red2[128 + idx];
      size_t o = ((size_t)b * LSPLIT + blockIdx.x) * K_ + k0 + idx;
      ws[O_PM + o] = mg;
      ws[O_PS + o] = sg;
    }
  }
}

// fused: combine chunk stats -> A[k]; w[l] = sum_k P16T[k,l]*A[k]
// (vector accumulation over k-slices, 16B coalesced reads, no shuffles);
// then wx[b,d] += sum_l w[l]*x16[l,d]  (inv applied in k_final)
__global__ __launch_bounds__(256) void k_wsumwx(float* ws) {
  int b = blockIdx.x, ch = blockIdx.y;
  int l0 = ch * 128;
  __shared__ float Al[512];
  __shared__ float wacc[16][128];
  __shared__ float wl[128];
  int tid = threadIdx.x;

  // combine: A[k] = exp(pm[ch,k] - M[k]) / S[k]
  for (int kk = tid; kk < K_; kk += 256) {
    float pmv[LSPLIT], psv[LSPLIT];
    float M = -INFINITY;
#pragma unroll
    for (int c = 0; c < LSPLIT; ++c) {
      pmv[c] = ws[O_PM + ((size_t)b * LSPLIT + c) * K_ + kk];
      psv[c] = ws[O_PS + ((size_t)b * LSPLIT + c) * K_ + kk];
      M = fmaxf(M, pmv[c]);
    }
    float S = 0.f;
#pragma unroll
    for (int c = 0; c < LSPLIT; ++c) S += psv[c] * expf(pmv[c] - M);
    Al[kk] = expf(pmv[ch] - M) / S;
  }
  __syncthreads();

  // w-partials: thread = (kslice = tid>>4 : 32 k's, lpart = tid&15 : 8 l's)
  const _Float16* pt = reinterpret_cast<const _Float16*>(ws + O_P16) +
                       (size_t)b * K_ * L_ + l0;
  int lpart = tid & 15, kslice = tid >> 4;
  float a8[8] = {0.f, 0.f, 0.f, 0.f, 0.f, 0.f, 0.f, 0.f};
  for (int k = kslice * 32; k < kslice * 32 + 32; ++k) {
    float ak = Al[k];
    f16x8 v = *reinterpret_cast<const f16x8*>(pt + (size_t)k * L_ + lpart * 8);
#pragma unroll
    for (int i = 0; i < 8; ++i) a8[i] += ak * (float)v[i];
  }
#pragma unroll
  for (int i = 0; i < 8; ++i) wacc[kslice][lpart * 8 + i] = a8[i];
  __syncthreads();
  if (tid < 128) {
    float s = 0.f;
#pragma unroll
    for (int sl = 0; sl < 16; ++sl) s += wacc[sl][tid];
    wl[tid] = s;
  }
  __syncthreads();

  const _Float16* x16b = reinterpret_cast<const _Float16*>(ws + O_X16) +
                         (size_t)(b * L_ + l0) * D_;
  int half = tid >> 7;            // 0/1 -> l 0..63 / 64..127
  int dd = (tid & 127) * 4;
  float4 a4 = {0.f, 0.f, 0.f, 0.f};
  for (int l = half * 64; l < half * 64 + 64; ++l) {
    float wgt = wl[l];
    f16x4 xv = *reinterpret_cast<const f16x4*>(x16b + (size_t)l * D_ + dd);
    a4.x += wgt * (float)xv[0];
    a4.y += wgt * (float)xv[1];
    a4.z += wgt * (float)xv[2];
    a4.w += wgt * (float)xv[3];
  }
  atomicAdd(&ws[O_WX + b * D_ + dd + 0], a4.x);
  atomicAdd(&ws[O_WX + b * D_ + dd + 1], a4.y);
  atomicAdd(&ws[O_WX + b * D_ + dd + 2], a4.z);
  atomicAdd(&ws[O_WX + b * D_ + dd + 3], a4.w);
}

// out[b,d] = (scale/L) * (inv*wx/K - meanC[d]),  inv = 1/max(scale/L, eps)
__global__ void k_final(const float* ws, float* out) {
  int i = blockIdx.x * 256 + threadIdx.x;
  int d = i & (D_ - 1);
  float sc = ws[O_SCALE + i] * (1.f / L_);
  float inv = 1.f / fmaxf(sc, EPS_);
  out[i] = sc * (inv * ws[O_WX + i] * (1.f / K_) - ws[O_MEANC + d]);
}

extern "C" void kernel_launch(void* const* d_in, const int* in_sizes, int n_in,
                              void* d_out, int out_size, void* d_ws, size_t ws_size,
                              hipStream_t stream) {
  const float* x = (const float*)d_in[0];
  const float* cent = (const float*)d_in[1];
  float* out = (float*)d_out;
  float* ws = (float*)d_ws;

  k_prep<<<130, 256, 0, stream>>>(cent, ws);
  k_sqacc<<<dim3(B_, D_ / 256, 8), 256, 0, stream>>>(x, ws);
  k_cfb<<<dim3(K_ * D_ / 1024, B_), 256, 0, stream>>>(cent, ws);
  k_gemm16<<<dim3(L_ / 128, K_ / 128, B_), 256, 0, stream>>>(ws);
  k_wsumwx<<<dim3(B_, LSPLIT), 256, 0, stream>>>(ws);
  k_final<<<B_ * D_ / 256, 256, 0, stream>>>(ws, out);
}

// Round 11
// 163.780 us; speedup vs baseline: 1.0526x; 1.0132x over previous
//
#include <hip/hip_runtime.h>
#include <math.h>

#define B_ 32
#define L_ 2048
#define D_ 512
#define K_ 512
#define CONC_ 100.0f
#define EPS_ 1e-12f
#define LSPLIT 16    // wsumwx chunks (128 l)
#define LSPLITG 8    // GEMM chunks (256 l)

typedef __attribute__((ext_vector_type(8))) _Float16 f16x8;
typedef __attribute__((ext_vector_type(4))) _Float16 f16x4;
typedef __attribute__((ext_vector_type(4))) float f32x4;

// ---- workspace layout (float offsets) ----
enum : size_t {
  O_SCALE = 0,                            // B*D  raw sum_l x^2
  O_MEANC = O_SCALE + B_*D_,              // D
  O_PM    = O_MEANC + D_,                 // B*LSPLITG*K  chunk max
  O_PS    = O_PM + (size_t)B_*LSPLITG*K_, // B*LSPLITG*K  chunk sum
  O_WX    = O_PS + (size_t)B_*LSPLITG*K_, // B*D
  O_CFB   = O_WX + B_*D_,                 // B*K*D halfs (200*cent*inv)
  O_X16   = O_CFB + (size_t)B_*K_*D_/2,   // B*L*D halfs (fp16 x, no inv)
  O_P16   = O_X16 + (size_t)B_*L_*D_/2,   // B*K*L halfs TRANSPOSED exp(v-m)
  WS_FLOATS = O_P16 + (size_t)B_*L_*K_/2
};

__device__ __forceinline__ void gl2lds16(const void* gsrc, void* lds) {
  __builtin_amdgcn_global_load_lds(
      (const __attribute__((address_space(1))) void*)gsrc,
      (__attribute__((address_space(3))) void*)lds, 16, 0, 0);
}

// prep: meanc (blk 0..1), zero scale (2..65), zero wx (66..129)
__global__ void k_prep(const float* __restrict__ cent, float* ws) {
  int blk = blockIdx.x, tid = threadIdx.x;
  if (blk < 2) {
    int d = blk * 256 + tid;
    float s = 0.f;
    for (int k = 0; k < K_; ++k) s += cent[(size_t)k * D_ + d];
    ws[O_MEANC + d] = s * (1.f / K_);
  } else if (blk < 66) {
    ws[O_SCALE + (blk - 2) * 256 + tid] = 0.f;
  } else {
    ws[O_WX + (blk - 66) * 256 + tid] = 0.f;
  }
}

// accumulate sum_l x^2 into scale AND emit x16 = fp16(x)
__global__ void k_sqacc(const float* __restrict__ x, float* ws) {
  int b = blockIdx.x, dc = blockIdx.y, lc = blockIdx.z;
  int d = dc * 256 + threadIdx.x;
  size_t base = ((size_t)b * L_ + lc * 256) * D_ + d;
  const float* xb = x + base;
  _Float16* x16b = reinterpret_cast<_Float16*>(ws + O_X16) + base;
  float acc = 0.f;
  for (int l = 0; l < 256; ++l) {
    float v = xb[(size_t)l * D_];
    acc += v * v;
    x16b[(size_t)l * D_] = (_Float16)v;
  }
  atomicAdd(&ws[O_SCALE + b * D_ + d], acc);
}

// cfb16[b,k,d] = fp16(200 * cent[k,d] / max(scale[b,d]/L, eps))
__global__ void k_cfb(const float* __restrict__ cent, float* ws) {
  int b = blockIdx.y;
  int f = (blockIdx.x * 256 + threadIdx.x) * 4;
  int d = f & (D_ - 1);
  float4 c = *reinterpret_cast<const float4*>(cent + f);
  float4 s4 = *reinterpret_cast<const float4*>(ws + O_SCALE + (size_t)b * D_ + d);
  f16x4 h;
  h[0] = (_Float16)(c.x * (2.f * CONC_) / fmaxf(s4.x * (1.f / L_), EPS_));
  h[1] = (_Float16)(c.y * (2.f * CONC_) / fmaxf(s4.y * (1.f / L_), EPS_));
  h[2] = (_Float16)(c.z * (2.f * CONC_) / fmaxf(s4.z * (1.f / L_), EPS_));
  h[3] = (_Float16)(c.w * (2.f * CONC_) / fmaxf(s4.w * (1.f / L_), EPS_));
  *reinterpret_cast<f16x4*>(
      reinterpret_cast<_Float16*>(ws + O_CFB) + (size_t)b * K_ * D_ + f) = h;
}

// 256x256 tile, BK=64, 8 waves (2M x 4N), wave = 128l x 64k, acc[8][4].
// Double-buffered LDS (128 KB), counted vmcnt(8), never 0 in loop.
// Bank fix: 16B-unit index XOR (row&7); staging dest linear (gl_lds rule),
// source pre-swizzled, reads swizzled. Fused softmax partials (chunk=256 l)
// + P16 transposed [b][k][l] store.
__global__ __launch_bounds__(512, 2) void k_gemm256(float* ws) {
  // XCD grouping: all 16 blocks of batch b land on XCD b&7
  const int id = blockIdx.x;            // 0..511
  const int xcd = id & 7, q = id >> 3;  // q 0..63
  const int b = xcd + (q >> 4) * 8;
  const int rest = q & 15;
  const int k0 = (rest >> 3) * 256;     // ntile 0/1
  const int mchunk = rest & 7;
  const int l0c = mchunk * 256;

  __shared__ _Float16 As[2][256 * 64];  // 2 x 32 KB
  __shared__ _Float16 Bs[2][256 * 64];  // 2 x 32 KB
  const int tid = threadIdx.x;
  const int lane = tid & 63;
  const int w = tid >> 6;               // 0..7
  const int wm = w >> 2, wn = w & 3;

  const _Float16* xb16 = reinterpret_cast<const _Float16*>(ws + O_X16) +
                         ((size_t)b * L_ + l0c) * D_;
  const _Float16* cfb = reinterpret_cast<const _Float16*>(ws + O_CFB) +
                        (size_t)b * K_ * D_ + (size_t)k0 * D_;

  f32x4 acc[8][4] = {};

  // staging indices: unit u = r*512+tid, row=u>>3, j=u&7, srccol=(j^(row&7))*8
#define STAGE(buf, kt)                                                         \
  {                                                                            \
    _Pragma("unroll") for (int r = 0; r < 4; ++r) {                            \
      int u = r * 512 + tid;                                                   \
      int row = u >> 3, j = u & 7;                                             \
      int sc = ((j ^ (row & 7)) << 3) + (kt) * 64;                             \
      gl2lds16(xb16 + (size_t)row * D_ + sc, &As[buf][(size_t)u * 8]);         \
      gl2lds16(cfb + (size_t)row * D_ + sc, &Bs[buf][(size_t)u * 8]);          \
    }                                                                          \
  }

#define COMPUTE(cb)                                                            \
  {                                                                            \
    const char* Ac = reinterpret_cast<const char*>(As[cb]);                    \
    const char* Bc = reinterpret_cast<const char*>(Bs[cb]);                    \
    _Pragma("unroll") for (int kk2 = 0; kk2 < 2; ++kk2) {                      \
      f16x8 bf[4];                                                             \
      _Pragma("unroll") for (int ni = 0; ni < 4; ++ni) {                       \
        int row = wn * 64 + ni * 16 + (lane & 15);                             \
        int un = ((kk2 << 2) | (lane >> 4)) ^ (row & 7);                       \
        bf[ni] = *reinterpret_cast<const f16x8*>(Bc + row * 128 + un * 16);    \
      }                                                                        \
      __builtin_amdgcn_s_setprio(1);                                           \
      _Pragma("unroll") for (int mi = 0; mi < 8; ++mi) {                       \
        int row = wm * 128 + mi * 16 + (lane & 15);                            \
        int un = ((kk2 << 2) | (lane >> 4)) ^ (row & 7);                       \
        f16x8 af = *reinterpret_cast<const f16x8*>(Ac + row * 128 + un * 16);  \
        _Pragma("unroll") for (int ni = 0; ni < 4; ++ni)                       \
          acc[mi][ni] = __builtin_amdgcn_mfma_f32_16x16x32_f16(                \
              af, bf[ni], acc[mi][ni], 0, 0, 0);                               \
      }                                                                        \
      __builtin_amdgcn_s_setprio(0);                                           \
    }                                                                          \
  }

  STAGE(0, 0);
  int cur = 0;
#pragma unroll 2
  for (int kt = 0; kt < 8; ++kt) {
    __builtin_amdgcn_s_barrier();             // prev reads of buf[cur^1] done
    if (kt < 7) {
      STAGE(cur ^ 1, kt + 1);
      asm volatile("s_waitcnt vmcnt(8)" ::: "memory");  // own cur loads done
    } else {
      asm volatile("s_waitcnt vmcnt(0)" ::: "memory");
    }
    __builtin_amdgcn_s_barrier();             // all waves' cur loads done
    COMPUTE(cur);
    cur ^= 1;
  }
#undef STAGE
#undef COMPUTE
  __syncthreads();   // all LDS reads done before As is reused as scratch

  // ---- fused softmax partials over this block's 256 l's ----
  float* red = reinterpret_cast<float*>(As);   // [2 wm][256 k]
  float* red2 = red + 512;                     // [2 wm][256 k]
  float pm[4], ps[4];
#pragma unroll
  for (int ni = 0; ni < 4; ++ni) {
    float m = -INFINITY;
#pragma unroll
    for (int mi = 0; mi < 8; ++mi)
#pragma unroll
      for (int j = 0; j < 4; ++j) m = fmaxf(m, acc[mi][ni][j]);
    m = fmaxf(m, __shfl_xor(m, 16));
    m = fmaxf(m, __shfl_xor(m, 32));
    pm[ni] = m;
  }
  if (lane < 16) {
#pragma unroll
    for (int ni = 0; ni < 4; ++ni)
      red[wm * 256 + wn * 64 + ni * 16 + lane] = pm[ni];
  }
  __syncthreads();
#pragma unroll
  for (int ni = 0; ni < 4; ++ni) {
    int idx = wn * 64 + ni * 16 + (lane & 15);
    pm[ni] = fmaxf(red[idx], red[256 + idx]);   // chunk max (256 l's)
  }
  // e = exp(v - m); sum AND store P16 transposed [b][k][l]
  _Float16* pg = reinterpret_cast<_Float16*>(ws + O_P16) + (size_t)b * K_ * L_;
#pragma unroll
  for (int ni = 0; ni < 4; ++ni) {
    int kc = k0 + wn * 64 + ni * 16 + (lane & 15);
    float s = 0.f;
#pragma unroll
    for (int mi = 0; mi < 8; ++mi) {
      int lr = l0c + wm * 128 + mi * 16 + (lane >> 4) * 4;
      f16x4 ev;
#pragma unroll
      for (int j = 0; j < 4; ++j) {
        float e = expf(acc[mi][ni][j] - pm[ni]);
        s += e;
        ev[j] = (_Float16)e;
      }
      *reinterpret_cast<f16x4*>(pg + (size_t)kc * L_ + lr) = ev;
    }
    s += __shfl_xor(s, 16);
    s += __shfl_xor(s, 32);
    ps[ni] = s;
  }
  if (lane < 16) {
#pragma unroll
    for (int ni = 0; ni < 4; ++ni)
      red2[wm * 256 + wn * 64 + ni * 16 + lane] = ps[ni];
  }
  __syncthreads();
  if (wm == 0 && lane < 16) {
#pragma unroll
    for (int ni = 0; ni < 4; ++ni) {
      int idx = wn * 64 + ni * 16 + lane;
      float mg = fmaxf(red[idx], red[256 + idx]);
      float sg = red2[idx] + red2[256 + idx];
      size_t o = ((size_t)b * LSPLITG + mchunk) * K_ + k0 + idx;
      ws[O_PM + o] = mg;
      ws[O_PS + o] = sg;
    }
  }
}

// fused: combine chunk stats -> A[k]; w[l] = sum_k P16T[k,l]*A[k];
// wx[b,d] += sum_l w[l]*x16[l,d]  (inv applied in k_final)
__global__ __launch_bounds__(256) void k_wsumwx(float* ws) {
  int b = blockIdx.x, ch = blockIdx.y;     // ch: 16 chunks of 128 l
  int l0 = ch * 128;
  __shared__ float Al[512];
  __shared__ float wacc[16][128];
  __shared__ float wl[128];
  int tid = threadIdx.x;
  int cg = ch >> 1;                        // GEMM chunk (256 l)

  for (int kk = tid; kk < K_; kk += 256) {
    float pmv[LSPLITG], psv[LSPLITG];
    float M = -INFINITY;
#pragma unroll
    for (int c = 0; c < LSPLITG; ++c) {
      pmv[c] = ws[O_PM + ((size_t)b * LSPLITG + c) * K_ + kk];
      psv[c] = ws[O_PS + ((size_t)b * LSPLITG + c) * K_ + kk];
      M = fmaxf(M, pmv[c]);
    }
    float S = 0.f;
#pragma unroll
    for (int c = 0; c < LSPLITG; ++c) S += psv[c] * expf(pmv[c] - M);
    Al[kk] = expf(pmv[cg] - M) / S;
  }
  __syncthreads();

  const _Float16* pt = reinterpret_cast<const _Float16*>(ws + O_P16) +
                       (size_t)b * K_ * L_ + l0;
  int lpart = tid & 15, kslice = tid >> 4;
  float a8[8] = {0.f, 0.f, 0.f, 0.f, 0.f, 0.f, 0.f, 0.f};
  for (int k = kslice * 32; k < kslice * 32 + 32; ++k) {
    float ak = Al[k];
    f16x8 v = *reinterpret_cast<const f16x8*>(pt + (size_t)k * L_ + lpart * 8);
#pragma unroll
    for (int i = 0; i < 8; ++i) a8[i] += ak * (float)v[i];
  }
#pragma unroll
  for (int i = 0; i < 8; ++i) wacc[kslice][lpart * 8 + i] = a8[i];
  __syncthreads();
  if (tid < 128) {
    float s = 0.f;
#pragma unroll
    for (int sl = 0; sl < 16; ++sl) s += wacc[sl][tid];
    wl[tid] = s;
  }
  __syncthreads();

  const _Float16* x16b = reinterpret_cast<const _Float16*>(ws + O_X16) +
                         (size_t)(b * L_ + l0) * D_;
  int half = tid >> 7;
  int dd = (tid & 127) * 4;
  float4 a4 = {0.f, 0.f, 0.f, 0.f};
  for (int l = half * 64; l < half * 64 + 64; ++l) {
    float wgt = wl[l];
    f16x4 xv = *reinterpret_cast<const f16x4*>(x16b + (size_t)l * D_ + dd);
    a4.x += wgt * (float)xv[0];
    a4.y += wgt * (float)xv[1];
    a4.z += wgt * (float)xv[2];
    a4.w += wgt * (float)xv[3];
  }
  atomicAdd(&ws[O_WX + b * D_ + dd + 0], a4.x);
  atomicAdd(&ws[O_WX + b * D_ + dd + 1], a4.y);
  atomicAdd(&ws[O_WX + b * D_ + dd + 2], a4.z);
  atomicAdd(&ws[O_WX + b * D_ + dd + 3], a4.w);
}

// out[b,d] = (scale/L) * (inv*wx/K - meanC[d])
__global__ void k_final(const float* ws, float* out) {
  int i = blockIdx.x * 256 + threadIdx.x;
  int d = i & (D_ - 1);
  float sc = ws[O_SCALE + i] * (1.f / L_);
  float inv = 1.f / fmaxf(sc, EPS_);
  out[i] = sc * (inv * ws[O_WX + i] * (1.f / K_) - ws[O_MEANC + d]);
}

extern "C" void kernel_launch(void* const* d_in, const int* in_sizes, int n_in,
                              void* d_out, int out_size, void* d_ws, size_t ws_size,
                              hipStream_t stream) {
  const float* x = (const float*)d_in[0];
  const float* cent = (const float*)d_in[1];
  float* out = (float*)d_out;
  float* ws = (float*)d_ws;

  k_prep<<<130, 256, 0, stream>>>(cent, ws);
  k_sqacc<<<dim3(B_, D_ / 256, 8), 256, 0, stream>>>(x, ws);
  k_cfb<<<dim3(K_ * D_ / 1024, B_), 256, 0, stream>>>(cent, ws);
  k_gemm256<<<512, 512, 0, stream>>>(ws);
  k_wsumwx<<<dim3(B_, LSPLIT), 256, 0, stream>>>(ws);
  k_final<<<B_ * D_ / 256, 256, 0, stream>>>(ws, out);
}

// Round 12
// 160.345 us; speedup vs baseline: 1.0751x; 1.0214x over previous
//
#include <hip/hip_runtime.h>
#include <math.h>

#define B_ 32
#define L_ 2048
#define D_ 512
#define K_ 512
#define CONC_ 100.0f
#define EPS_ 1e-12f
#define LSPLIT 16            // 16 chunks of 128 l's (= GEMM l-tile)
#define EXPSCALE 1.44269504088896f   // log2(e); folded into cfb

typedef __attribute__((ext_vector_type(8))) _Float16 f16x8;
typedef __attribute__((ext_vector_type(4))) _Float16 f16x4;
typedef __attribute__((ext_vector_type(4))) float f32x4;

// ---- workspace layout (float offsets) ----
enum : size_t {
  O_SCALE = 0,                            // B*D  raw sum_l x^2
  O_MEANC = O_SCALE + B_*D_,              // D
  O_PM    = O_MEANC + D_,                 // B*LSPLIT*K  chunk max (log2 units)
  O_PS    = O_PM + (size_t)B_*LSPLIT*K_,  // B*LSPLIT*K  chunk sum
  O_WX    = O_PS + (size_t)B_*LSPLIT*K_,  // B*D
  O_CFB   = O_WX + B_*D_,                 // B*K*D halfs (200*log2e*cent*inv)
  O_X16   = O_CFB + (size_t)B_*K_*D_/2,   // B*L*D halfs (fp16 x)
  O_P16   = O_X16 + (size_t)B_*L_*D_/2,   // B*K*L halfs TRANSPOSED exp2(v-m)
  WS_FLOATS = O_P16 + (size_t)B_*L_*K_/2
};

__device__ __forceinline__ void gl2lds16(const void* gsrc, void* lds) {
  __builtin_amdgcn_global_load_lds(
      (const __attribute__((address_space(1))) void*)gsrc,
      (__attribute__((address_space(3))) void*)lds, 16, 0, 0);
}

// prep: meanc (blk 0..1), zero scale (2..65), zero wx (66..129)
__global__ void k_prep(const float* __restrict__ cent, float* ws) {
  int blk = blockIdx.x, tid = threadIdx.x;
  if (blk < 2) {
    int d = blk * 256 + tid;
    float s = 0.f;
    for (int k = 0; k < K_; ++k) s += cent[(size_t)k * D_ + d];
    ws[O_MEANC + d] = s * (1.f / K_);
  } else if (blk < 66) {
    ws[O_SCALE + (blk - 2) * 256 + tid] = 0.f;
  } else {
    ws[O_WX + (blk - 66) * 256 + tid] = 0.f;
  }
}

// accumulate sum_l x^2 into scale AND emit x16 = fp16(x)
__global__ void k_sqacc(const float* __restrict__ x, float* ws) {
  int b = blockIdx.x, dc = blockIdx.y, lc = blockIdx.z;
  int d = dc * 256 + threadIdx.x;
  size_t base = ((size_t)b * L_ + lc * 256) * D_ + d;
  const float* xb = x + base;
  _Float16* x16b = reinterpret_cast<_Float16*>(ws + O_X16) + base;
  float acc = 0.f;
  for (int l = 0; l < 256; ++l) {
    float v = xb[(size_t)l * D_];
    acc += v * v;
    x16b[(size_t)l * D_] = (_Float16)v;
  }
  atomicAdd(&ws[O_SCALE + b * D_ + d], acc);
}

// cfb16[b,k,d] = fp16(200*log2e * cent[k,d] / max(scale[b,d]/L, eps))
__global__ void k_cfb(const float* __restrict__ cent, float* ws) {
  int b = blockIdx.y;
  int f = (blockIdx.x * 256 + threadIdx.x) * 4;
  int d = f & (D_ - 1);
  float4 c = *reinterpret_cast<const float4*>(cent + f);
  float4 s4 = *reinterpret_cast<const float4*>(ws + O_SCALE + (size_t)b * D_ + d);
  const float sc = 2.f * CONC_ * EXPSCALE;
  f16x4 h;
  h[0] = (_Float16)(c.x * sc / fmaxf(s4.x * (1.f / L_), EPS_));
  h[1] = (_Float16)(c.y * sc / fmaxf(s4.y * (1.f / L_), EPS_));
  h[2] = (_Float16)(c.z * sc / fmaxf(s4.z * (1.f / L_), EPS_));
  h[3] = (_Float16)(c.w * sc / fmaxf(s4.w * (1.f / L_), EPS_));
  *reinterpret_cast<f16x4*>(
      reinterpret_cast<_Float16*>(ws + O_CFB) + (size_t)b * K_ * D_ + f) = h;
}

// MFMA GEMM (log2-domain logits): v'[l,k] = sum_d x16[l,d]*cfb16[k,d].
// Single-buffered 128x128, BK=32, 4 waves (2x2), acc[4][4] — r4-proven
// structure (cross-block TLP beats in-block pipelining at this shape).
// Fused epilogue: chunk softmax partials (exp2) + P16 transposed [b][k][l].
// Grid 2048 1D, XCD-grouped: each XCD owns 4 b's -> cfb/x16 L2-resident.
__global__ __launch_bounds__(256) void k_gemm16(float* ws) {
  const int id = blockIdx.x;            // 0..2047
  const int xcd = id & 7;
  const int r = id >> 3;                // 0..255
  const int b = xcd + ((r >> 6) << 3);  // XCD owns b = xcd, xcd+8, +16, +24
  const int lk = r & 63;
  const int lchunk = lk & 15;
  const int l0 = lchunk * 128;
  const int k0 = (lk >> 4) * 128;

  __shared__ _Float16 As[128 * 32];   // 8 KB
  __shared__ _Float16 Bs[128 * 32];   // 8 KB
  const int tid = threadIdx.x;
  const int lane = tid & 63;
  const int w = tid >> 6;
  const int wm = w >> 1, wn = w & 1;

  const _Float16* xb16 = reinterpret_cast<const _Float16*>(ws + O_X16) +
                         (size_t)b * L_ * D_;
  const _Float16* cfb = reinterpret_cast<const _Float16*>(ws + O_CFB) +
                        (size_t)b * K_ * D_;

  f32x4 acc[4][4] = {};

  for (int d0 = 0; d0 < D_; d0 += 32) {
#pragma unroll
    for (int rr = 0; rr < 2; ++rr) {
      int u = rr * 256 + tid;              // 16B unit 0..511
      int row = u >> 2, slot = u & 3;
      int sc = (slot ^ ((row >> 1) & 3)) * 8;
      gl2lds16(xb16 + (size_t)(l0 + row) * D_ + d0 + sc, As + (size_t)u * 8);
    }
#pragma unroll
    for (int rr = 0; rr < 2; ++rr) {
      int u = rr * 256 + tid;
      int row = u >> 2, slot = u & 3;
      int sc = (slot ^ ((row >> 1) & 3)) * 8;
      gl2lds16(cfb + (size_t)(k0 + row) * D_ + d0 + sc, Bs + (size_t)u * 8);
    }
    __syncthreads();

    f16x8 af[4], bfr[4];
#pragma unroll
    for (int mi = 0; mi < 4; ++mi) {
      int row = wm * 64 + mi * 16 + (lane & 15);
      int sw = (lane >> 4) ^ ((row >> 1) & 3);
      af[mi] = *reinterpret_cast<const f16x8*>(
          reinterpret_cast<const char*>(As) + row * 64 + sw * 16);
    }
#pragma unroll
    for (int ni = 0; ni < 4; ++ni) {
      int row = wn * 64 + ni * 16 + (lane & 15);
      int sw = (lane >> 4) ^ ((row >> 1) & 3);
      bfr[ni] = *reinterpret_cast<const f16x8*>(
          reinterpret_cast<const char*>(Bs) + row * 64 + sw * 16);
    }
#pragma unroll
    for (int mi = 0; mi < 4; ++mi)
#pragma unroll
      for (int ni = 0; ni < 4; ++ni)
        acc[mi][ni] = __builtin_amdgcn_mfma_f32_16x16x32_f16(
            af[mi], bfr[ni], acc[mi][ni], 0, 0, 0);
    __syncthreads();
  }

  // ---- fused softmax partials over this block's 128 l's (log2 domain) ----
  // (bias[k] omitted: constant over l, cancels in softmax over l)
  float* red = reinterpret_cast<float*>(As);   // [2 wm][128 k] wave maxes
  float* red2 = red + 256;                     // [2 wm][128 k] wave sums
  float pm[4], ps[4];
#pragma unroll
  for (int ni = 0; ni < 4; ++ni) {
    float m = -INFINITY;
#pragma unroll
    for (int mi = 0; mi < 4; ++mi)
#pragma unroll
      for (int j = 0; j < 4; ++j) m = fmaxf(m, acc[mi][ni][j]);
    m = fmaxf(m, __shfl_xor(m, 16));
    m = fmaxf(m, __shfl_xor(m, 32));
    pm[ni] = m;
  }
  if (lane < 16) {
#pragma unroll
    for (int ni = 0; ni < 4; ++ni)
      red[wm * 128 + wn * 64 + ni * 16 + lane] = pm[ni];
  }
  __syncthreads();
#pragma unroll
  for (int ni = 0; ni < 4; ++ni) {
    int idx = wn * 64 + ni * 16 + (lane & 15);
    pm[ni] = fmaxf(red[idx], red[128 + idx]);   // combined chunk max
  }
  // e = exp2(v' - m'); accumulate sum AND store P16 TRANSPOSED [b][k][l]
  _Float16* pg = reinterpret_cast<_Float16*>(ws + O_P16) + (size_t)b * K_ * L_;
#pragma unroll
  for (int ni = 0; ni < 4; ++ni) {
    int kc = k0 + wn * 64 + ni * 16 + (lane & 15);
    float s = 0.f;
#pragma unroll
    for (int mi = 0; mi < 4; ++mi) {
      int lr = l0 + wm * 64 + mi * 16 + (lane >> 4) * 4;
      f16x4 ev;
#pragma unroll
      for (int j = 0; j < 4; ++j) {
        float e = exp2f(acc[mi][ni][j] - pm[ni]);
        s += e;
        ev[j] = (_Float16)e;
      }
      *reinterpret_cast<f16x4*>(pg + (size_t)kc * L_ + lr) = ev;
    }
    s += __shfl_xor(s, 16);
    s += __shfl_xor(s, 32);
    ps[ni] = s;
  }
  if (lane < 16) {
#pragma unroll
    for (int ni = 0; ni < 4; ++ni)
      red2[wm * 128 + wn * 64 + ni * 16 + lane] = ps[ni];
  }
  __syncthreads();
  if (w < 2 && lane < 16) {
#pragma unroll
    for (int ni = 0; ni < 4; ++ni) {
      int idx = wn * 64 + ni * 16 + lane;
      float mg = fmaxf(red[idx], red[128 + idx]);
      float sg = red2[idx] + red2[128 + idx];
      size_t o = ((size_t)b * LSPLIT + lchunk) * K_ + k0 + idx;
      ws[O_PM + o] = mg;
      ws[O_PS + o] = sg;
    }
  }
}

// fused: combine chunk stats -> A[k] (exp2); w[l] = sum_k P16T[k,l]*A[k]
// (coalesced k-slice accumulation); wx[b,d] += sum_l w[l]*x16[l,d]
__global__ __launch_bounds__(256) void k_wsumwx(float* ws) {
  int b = blockIdx.x, ch = blockIdx.y;
  int l0 = ch * 128;
  __shared__ float Al[512];
  __shared__ float wacc[16][128];
  __shared__ float wl[128];
  int tid = threadIdx.x;

  // combine: A[k] = exp2(pm[ch,k] - M[k]) / S[k]
  for (int kk = tid; kk < K_; kk += 256) {
    float pmv[LSPLIT], psv[LSPLIT];
    float M = -INFINITY;
#pragma unroll
    for (int c = 0; c < LSPLIT; ++c) {
      pmv[c] = ws[O_PM + ((size_t)b * LSPLIT + c) * K_ + kk];
      psv[c] = ws[O_PS + ((size_t)b * LSPLIT + c) * K_ + kk];
      M = fmaxf(M, pmv[c]);
    }
    float S = 0.f;
#pragma unroll
    for (int c = 0; c < LSPLIT; ++c) S += psv[c] * exp2f(pmv[c] - M);
    Al[kk] = exp2f(pmv[ch] - M) / S;
  }
  __syncthreads();

  // w-partials: thread = (kslice = tid>>4 : 32 k's, lpart = tid&15 : 8 l's)
  const _Float16* pt = reinterpret_cast<const _Float16*>(ws + O_P16) +
                       (size_t)b * K_ * L_ + l0;
  int lpart = tid & 15, kslice = tid >> 4;
  float a8[8] = {0.f, 0.f, 0.f, 0.f, 0.f, 0.f, 0.f, 0.f};
  for (int k = kslice * 32; k < kslice * 32 + 32; ++k) {
    float ak = Al[k];
    f16x8 v = *reinterpret_cast<const f16x8*>(pt + (size_t)k * L_ + lpart * 8);
#pragma unroll
    for (int i = 0; i < 8; ++i) a8[i] += ak * (float)v[i];
  }
#pragma unroll
  for (int i = 0; i < 8; ++i) wacc[kslice][lpart * 8 + i] = a8[i];
  __syncthreads();
  if (tid < 128) {
    float s = 0.f;
#pragma unroll
    for (int sl = 0; sl < 16; ++sl) s += wacc[sl][tid];
    wl[tid] = s;
  }
  __syncthreads();

  const _Float16* x16b = reinterpret_cast<const _Float16*>(ws + O_X16) +
                         (size_t)(b * L_ + l0) * D_;
  int half = tid >> 7;
  int dd = (tid & 127) * 4;
  float4 a4 = {0.f, 0.f, 0.f, 0.f};
  for (int l = half * 64; l < half * 64 + 64; ++l) {
    float wgt = wl[l];
    f16x4 xv = *reinterpret_cast<const f16x4*>(x16b + (size_t)l * D_ + dd);
    a4.x += wgt * (float)xv[0];
    a4.y += wgt * (float)xv[1];
    a4.z += wgt * (float)xv[2];
    a4.w += wgt * (float)xv[3];
  }
  atomicAdd(&ws[O_WX + b * D_ + dd + 0], a4.x);
  atomicAdd(&ws[O_WX + b * D_ + dd + 1], a4.y);
  atomicAdd(&ws[O_WX + b * D_ + dd + 2], a4.z);
  atomicAdd(&ws[O_WX + b * D_ + dd + 3], a4.w);
}

// out[b,d] = (scale/L) * (inv*wx/K - meanC[d])
__global__ void k_final(const float* ws, float* out) {
  int i = blockIdx.x * 256 + threadIdx.x;
  int d = i & (D_ - 1);
  float sc = ws[O_SCALE + i] * (1.f / L_);
  float inv = 1.f / fmaxf(sc, EPS_);
  out[i] = sc * (inv * ws[O_WX + i] * (1.f / K_) - ws[O_MEANC + d]);
}

extern "C" void kernel_launch(void* const* d_in, const int* in_sizes, int n_in,
                              void* d_out, int out_size, void* d_ws, size_t ws_size,
                              hipStream_t stream) {
  const float* x = (const float*)d_in[0];
  const float* cent = (const float*)d_in[1];
  float* out = (float*)d_out;
  float* ws = (float*)d_ws;

  k_prep<<<130, 256, 0, stream>>>(cent, ws);
  k_sqacc<<<dim3(B_, D_ / 256, 8), 256, 0, stream>>>(x, ws);
  k_cfb<<<dim3(K_ * D_ / 1024, B_), 256, 0, stream>>>(cent, ws);
  k_gemm16<<<2048, 256, 0, stream>>>(ws);
  k_wsumwx<<<dim3(B_, LSPLIT), 256, 0, stream>>>(ws);
  k_final<<<B_ * D_ / 256, 256, 0, stream>>>(ws, out);
}

// Round 13
// 151.341 us; speedup vs baseline: 1.1391x; 1.0595x over previous
//
#include <hip/hip_runtime.h>
#include <math.h>

#define B_ 32
#define L_ 2048
#define D_ 512
#define K_ 512
#define CONC_ 100.0f
#define EPS_ 1e-12f
#define LSPLIT 16            // 16 chunks of 128 l's (= GEMM l-tile)
#define EXPSCALE 1.44269504088896f   // log2(e); folded into cfb

typedef __attribute__((ext_vector_type(8))) _Float16 f16x8;
typedef __attribute__((ext_vector_type(4))) _Float16 f16x4;
typedef __attribute__((ext_vector_type(4))) float f32x4;

// ---- workspace layout (float offsets) ----
enum : size_t {
  O_SCALE = 0,                            // B*D  raw sum_l x^2
  O_MEANC = O_SCALE + B_*D_,              // D
  O_PM    = O_MEANC + D_,                 // B*LSPLIT*K  chunk max (log2 units)
  O_PS    = O_PM + (size_t)B_*LSPLIT*K_,  // B*LSPLIT*K  chunk sum
  O_WX    = O_PS + (size_t)B_*LSPLIT*K_,  // B*D
  O_CFB   = O_WX + B_*D_,                 // B*K*D halfs (200*log2e*cent*inv)
  O_X16   = O_CFB + (size_t)B_*K_*D_/2,   // B*L*D halfs (fp16 x)
  O_P16   = O_X16 + (size_t)B_*L_*D_/2,   // B*K*L halfs TRANSPOSED exp2(v-m)
  WS_FLOATS = O_P16 + (size_t)B_*L_*K_/2
};

__device__ __forceinline__ void gl2lds16(const void* gsrc, void* lds) {
  __builtin_amdgcn_global_load_lds(
      (const __attribute__((address_space(1))) void*)gsrc,
      (__attribute__((address_space(3))) void*)lds, 16, 0, 0);
}

// prep: meanc (blk 0..1), zero scale (2..65), zero wx (66..129)
__global__ void k_prep(const float* __restrict__ cent, float* ws) {
  int blk = blockIdx.x, tid = threadIdx.x;
  if (blk < 2) {
    int d = blk * 256 + tid;
    float s = 0.f;
    for (int k = 0; k < K_; ++k) s += cent[(size_t)k * D_ + d];
    ws[O_MEANC + d] = s * (1.f / K_);
  } else if (blk < 66) {
    ws[O_SCALE + (blk - 2) * 256 + tid] = 0.f;
  } else {
    ws[O_WX + (blk - 66) * 256 + tid] = 0.f;
  }
}

// accumulate sum_l x^2 into scale AND emit x16 = fp16(x)
__global__ void k_sqacc(const float* __restrict__ x, float* ws) {
  int b = blockIdx.x, dc = blockIdx.y, lc = blockIdx.z;
  int d = dc * 256 + threadIdx.x;
  size_t base = ((size_t)b * L_ + lc * 256) * D_ + d;
  const float* xb = x + base;
  _Float16* x16b = reinterpret_cast<_Float16*>(ws + O_X16) + base;
  float acc = 0.f;
  for (int l = 0; l < 256; ++l) {
    float v = xb[(size_t)l * D_];
    acc += v * v;
    x16b[(size_t)l * D_] = (_Float16)v;
  }
  atomicAdd(&ws[O_SCALE + b * D_ + d], acc);
}

// cfb16[b,k,d] = fp16(200*log2e * cent[k,d] / max(scale[b,d]/L, eps))
__global__ void k_cfb(const float* __restrict__ cent, float* ws) {
  int b = blockIdx.y;
  int f = (blockIdx.x * 256 + threadIdx.x) * 4;
  int d = f & (D_ - 1);
  float4 c = *reinterpret_cast<const float4*>(cent + f);
  float4 s4 = *reinterpret_cast<const float4*>(ws + O_SCALE + (size_t)b * D_ + d);
  const float sc = 2.f * CONC_ * EXPSCALE;
  f16x4 h;
  h[0] = (_Float16)(c.x * sc / fmaxf(s4.x * (1.f / L_), EPS_));
  h[1] = (_Float16)(c.y * sc / fmaxf(s4.y * (1.f / L_), EPS_));
  h[2] = (_Float16)(c.z * sc / fmaxf(s4.z * (1.f / L_), EPS_));
  h[3] = (_Float16)(c.w * sc / fmaxf(s4.w * (1.f / L_), EPS_));
  *reinterpret_cast<f16x4*>(
      reinterpret_cast<_Float16*>(ws + O_CFB) + (size_t)b * K_ * D_ + f) = h;
}

// MFMA GEMM (log2-domain logits), single-buffered 128x128, BK=64:
// 32 MFMA + 16 ds_read per 2 barriers (2x the MFMA:barrier ratio of BK=32).
// LDS rows = 128 B, 8 slots; swizzle sw = slot ^ (row&7); staging dest
// linear (gl_lds rule), source inverse-swizzled. 4 waves (2x2), acc[4][4].
// Fused epilogue: chunk softmax partials (exp2) + P16 transposed [b][k][l].
// Grid 2048 1D, XCD-grouped: each XCD owns 4 b's -> cfb/x16 L2-resident.
__global__ __launch_bounds__(256, 3) void k_gemm16(float* ws) {
  const int id = blockIdx.x;            // 0..2047
  const int xcd = id & 7;
  const int r = id >> 3;                // 0..255
  const int b = xcd + ((r >> 6) << 3);  // XCD owns b = xcd, xcd+8, +16, +24
  const int lk = r & 63;
  const int lchunk = lk & 15;
  const int l0 = lchunk * 128;
  const int k0 = (lk >> 4) * 128;

  __shared__ _Float16 As[128 * 64];   // 16 KB
  __shared__ _Float16 Bs[128 * 64];   // 16 KB
  const int tid = threadIdx.x;
  const int lane = tid & 63;
  const int w = tid >> 6;
  const int wm = w >> 1, wn = w & 1;

  const _Float16* xb16 = reinterpret_cast<const _Float16*>(ws + O_X16) +
                         (size_t)b * L_ * D_;
  const _Float16* cfb = reinterpret_cast<const _Float16*>(ws + O_CFB) +
                        (size_t)b * K_ * D_;

  f32x4 acc[4][4] = {};

  for (int d0 = 0; d0 < D_; d0 += 64) {
    // stage: 1024 16B-units per operand; dest linear, source inverse-swizzled
#pragma unroll
    for (int rr = 0; rr < 4; ++rr) {
      int u = rr * 256 + tid;              // unit 0..1023
      int row = u >> 3, j = u & 7;
      int sc = ((j ^ (row & 7)) << 3);     // halfs
      gl2lds16(xb16 + (size_t)(l0 + row) * D_ + d0 + sc, As + (size_t)u * 8);
    }
#pragma unroll
    for (int rr = 0; rr < 4; ++rr) {
      int u = rr * 256 + tid;
      int row = u >> 3, j = u & 7;
      int sc = ((j ^ (row & 7)) << 3);
      gl2lds16(cfb + (size_t)(k0 + row) * D_ + d0 + sc, Bs + (size_t)u * 8);
    }
    __syncthreads();

#pragma unroll
    for (int kk = 0; kk < 2; ++kk) {       // two K=32 halves of the BK=64 tile
      f16x8 af[4], bfr[4];
#pragma unroll
      for (int mi = 0; mi < 4; ++mi) {
        int row = wm * 64 + mi * 16 + (lane & 15);
        int slot = kk * 4 + (lane >> 4);
        int sw = slot ^ (row & 7);
        af[mi] = *reinterpret_cast<const f16x8*>(
            reinterpret_cast<const char*>(As) + row * 128 + sw * 16);
      }
#pragma unroll
      for (int ni = 0; ni < 4; ++ni) {
        int row = wn * 64 + ni * 16 + (lane & 15);
        int slot = kk * 4 + (lane >> 4);
        int sw = slot ^ (row & 7);
        bfr[ni] = *reinterpret_cast<const f16x8*>(
            reinterpret_cast<const char*>(Bs) + row * 128 + sw * 16);
      }
#pragma unroll
      for (int mi = 0; mi < 4; ++mi)
#pragma unroll
        for (int ni = 0; ni < 4; ++ni)
          acc[mi][ni] = __builtin_amdgcn_mfma_f32_16x16x32_f16(
              af[mi], bfr[ni], acc[mi][ni], 0, 0, 0);
    }
    __syncthreads();
  }

  // ---- fused softmax partials over this block's 128 l's (log2 domain) ----
  // (bias[k] omitted: constant over l, cancels in softmax over l)
  float* red = reinterpret_cast<float*>(As);   // [2 wm][128 k] wave maxes
  float* red2 = red + 256;                     // [2 wm][128 k] wave sums
  float pm[4], ps[4];
#pragma unroll
  for (int ni = 0; ni < 4; ++ni) {
    float m = -INFINITY;
#pragma unroll
    for (int mi = 0; mi < 4; ++mi)
#pragma unroll
      for (int j = 0; j < 4; ++j) m = fmaxf(m, acc[mi][ni][j]);
    m = fmaxf(m, __shfl_xor(m, 16));
    m = fmaxf(m, __shfl_xor(m, 32));
    pm[ni] = m;
  }
  if (lane < 16) {
#pragma unroll
    for (int ni = 0; ni < 4; ++ni)
      red[wm * 128 + wn * 64 + ni * 16 + lane] = pm[ni];
  }
  __syncthreads();
#pragma unroll
  for (int ni = 0; ni < 4; ++ni) {
    int idx = wn * 64 + ni * 16 + (lane & 15);
    pm[ni] = fmaxf(red[idx], red[128 + idx]);   // combined chunk max
  }
  // e = exp2(v' - m'); accumulate sum AND store P16 TRANSPOSED [b][k][l]
  _Float16* pg = reinterpret_cast<_Float16*>(ws + O_P16) + (size_t)b * K_ * L_;
#pragma unroll
  for (int ni = 0; ni < 4; ++ni) {
    int kc = k0 + wn * 64 + ni * 16 + (lane & 15);
    float s = 0.f;
#pragma unroll
    for (int mi = 0; mi < 4; ++mi) {
      int lr = l0 + wm * 64 + mi * 16 + (lane >> 4) * 4;
      f16x4 ev;
#pragma unroll
      for (int j = 0; j < 4; ++j) {
        float e = exp2f(acc[mi][ni][j] - pm[ni]);
        s += e;
        ev[j] = (_Float16)e;
      }
      *reinterpret_cast<f16x4*>(pg + (size_t)kc * L_ + lr) = ev;
    }
    s += __shfl_xor(s, 16);
    s += __shfl_xor(s, 32);
    ps[ni] = s;
  }
  if (lane < 16) {
#pragma unroll
    for (int ni = 0; ni < 4; ++ni)
      red2[wm * 128 + wn * 64 + ni * 16 + lane] = ps[ni];
  }
  __syncthreads();
  if (w < 2 && lane < 16) {
#pragma unroll
    for (int ni = 0; ni < 4; ++ni) {
      int idx = wn * 64 + ni * 16 + lane;
      float mg = fmaxf(red[idx], red[128 + idx]);
      float sg = red2[idx] + red2[128 + idx];
      size_t o = ((size_t)b * LSPLIT + lchunk) * K_ + k0 + idx;
      ws[O_PM + o] = mg;
      ws[O_PS + o] = sg;
    }
  }
}

// fused: combine chunk stats -> A[k] (exp2); w[l] = sum_k P16T[k,l]*A[k]
// (coalesced k-slice accumulation); wx[b,d] += sum_l w[l]*x16[l,d]
__global__ __launch_bounds__(256) void k_wsumwx(float* ws) {
  int b = blockIdx.x, ch = blockIdx.y;
  int l0 = ch * 128;
  __shared__ float Al[512];
  __shared__ float wacc[16][128];
  __shared__ float wl[128];
  int tid = threadIdx.x;

  // combine: A[k] = exp2(pm[ch,k] - M[k]) / S[k]
  for (int kk = tid; kk < K_; kk += 256) {
    float pmv[LSPLIT], psv[LSPLIT];
    float M = -INFINITY;
#pragma unroll
    for (int c = 0; c < LSPLIT; ++c) {
      pmv[c] = ws[O_PM + ((size_t)b * LSPLIT + c) * K_ + kk];
      psv[c] = ws[O_PS + ((size_t)b * LSPLIT + c) * K_ + kk];
      M = fmaxf(M, pmv[c]);
    }
    float S = 0.f;
#pragma unroll
    for (int c = 0; c < LSPLIT; ++c) S += psv[c] * exp2f(pmv[c] - M);
    Al[kk] = exp2f(pmv[ch] - M) / S;
  }
  __syncthreads();

  // w-partials: thread = (kslice = tid>>4 : 32 k's, lpart = tid&15 : 8 l's)
  const _Float16* pt = reinterpret_cast<const _Float16*>(ws + O_P16) +
                       (size_t)b * K_ * L_ + l0;
  int lpart = tid & 15, kslice = tid >> 4;
  float a8[8] = {0.f, 0.f, 0.f, 0.f, 0.f, 0.f, 0.f, 0.f};
  for (int k = kslice * 32; k < kslice * 32 + 32; ++k) {
    float ak = Al[k];
    f16x8 v = *reinterpret_cast<const f16x8*>(pt + (size_t)k * L_ + lpart * 8);
#pragma unroll
    for (int i = 0; i < 8; ++i) a8[i] += ak * (float)v[i];
  }
#pragma unroll
  for (int i = 0; i < 8; ++i) wacc[kslice][lpart * 8 + i] = a8[i];
  __syncthreads();
  if (tid < 128) {
    float s = 0.f;
#pragma unroll
    for (int sl = 0; sl < 16; ++sl) s += wacc[sl][tid];
    wl[tid] = s;
  }
  __syncthreads();

  const _Float16* x16b = reinterpret_cast<const _Float16*>(ws + O_X16) +
                         (size_t)(b * L_ + l0) * D_;
  int half = tid >> 7;
  int dd = (tid & 127) * 4;
  float4 a4 = {0.f, 0.f, 0.f, 0.f};
  for (int l = half * 64; l < half * 64 + 64; ++l) {
    float wgt = wl[l];
    f16x4 xv = *reinterpret_cast<const f16x4*>(x16b + (size_t)l * D_ + dd);
    a4.x += wgt * (float)xv[0];
    a4.y += wgt * (float)xv[1];
    a4.z += wgt * (float)xv[2];
    a4.w += wgt * (float)xv[3];
  }
  atomicAdd(&ws[O_WX + b * D_ + dd + 0], a4.x);
  atomicAdd(&ws[O_WX + b * D_ + dd + 1], a4.y);
  atomicAdd(&ws[O_WX + b * D_ + dd + 2], a4.z);
  atomicAdd(&ws[O_WX + b * D_ + dd + 3], a4.w);
}

// out[b,d] = (scale/L) * (inv*wx/K - meanC[d])
__global__ void k_final(const float* ws, float* out) {
  int i = blockIdx.x * 256 + threadIdx.x;
  int d = i & (D_ - 1);
  float sc = ws[O_SCALE + i] * (1.f / L_);
  float inv = 1.f / fmaxf(sc, EPS_);
  out[i] = sc * (inv * ws[O_WX + i] * (1.f / K_) - ws[O_MEANC + d]);
}

extern "C" void kernel_launch(void* const* d_in, const int* in_sizes, int n_in,
                              void* d_out, int out_size, void* d_ws, size_t ws_size,
                              hipStream_t stream) {
  const float* x = (const float*)d_in[0];
  const float* cent = (const float*)d_in[1];
  float* out = (float*)d_out;
  float* ws = (float*)d_ws;

  k_prep<<<130, 256, 0, stream>>>(cent, ws);
  k_sqacc<<<dim3(B_, D_ / 256, 8), 256, 0, stream>>>(x, ws);
  k_cfb<<<dim3(K_ * D_ / 1024, B_), 256, 0, stream>>>(cent, ws);
  k_gemm16<<<2048, 256, 0, stream>>>(ws);
  k_wsumwx<<<dim3(B_, LSPLIT), 256, 0, stream>>>(ws);
  k_final<<<B_ * D_ / 256, 256, 0, stream>>>(ws, out);
}

// Round 14
// 147.962 us; speedup vs baseline: 1.1651x; 1.0228x over previous
//
#include <hip/hip_runtime.h>
#include <math.h>

#define B_ 32
#define L_ 2048
#define D_ 512
#define K_ 512
#define CONC_ 100.0f
#define EPS_ 1e-12f
#define LSPLIT 16            // 16 chunks of 128 l's (= GEMM l-tile)
#define EXPSCALE 1.44269504088896f   // log2(e); folded into cfb

typedef __attribute__((ext_vector_type(8))) _Float16 f16x8;
typedef __attribute__((ext_vector_type(4))) _Float16 f16x4;
typedef __attribute__((ext_vector_type(4))) float f32x4;

// ---- workspace layout (float offsets) ----
enum : size_t {
  O_MEANC = 0,                            // D
  O_PM    = O_MEANC + D_,                 // B*LSPLIT*K  chunk max (log2 units)
  O_PS    = O_PM + (size_t)B_*LSPLIT*K_,  // B*LSPLIT*K  chunk sum
  O_SCP   = O_PS + (size_t)B_*LSPLIT*K_,  // B*8*D   x^2 partials (no atomics)
  O_WXP   = O_SCP + (size_t)B_*8*D_,      // B*16*D  wx partials (no atomics)
  O_CFB   = O_WXP + (size_t)B_*16*D_,     // B*K*D halfs (200*log2e*cent*inv)
  O_X16   = O_CFB + (size_t)B_*K_*D_/2,   // B*L*D halfs (fp16 x)
  O_P16   = O_X16 + (size_t)B_*L_*D_/2,   // B*K*L halfs TRANSPOSED exp2(v-m)
  WS_FLOATS = O_P16 + (size_t)B_*L_*K_/2
};

__device__ __forceinline__ void gl2lds16(const void* gsrc, void* lds) {
  __builtin_amdgcn_global_load_lds(
      (const __attribute__((address_space(1))) void*)gsrc,
      (__attribute__((address_space(3))) void*)lds, 16, 0, 0);
}

// meanC[d] = mean_k cent[k,d]
__global__ void k_meanc(const float* __restrict__ cent, float* ws) {
  int d = blockIdx.x * 256 + threadIdx.x;
  float s = 0.f;
  for (int k = 0; k < K_; ++k) s += cent[(size_t)k * D_ + d];
  ws[O_MEANC + d] = s * (1.f / K_);
}

// x^2 partial sums (plain stores, no zero/atomics) AND x16 = fp16(x)
__global__ void k_sqacc(const float* __restrict__ x, float* ws) {
  int b = blockIdx.x, dc = blockIdx.y, lc = blockIdx.z;
  int d = dc * 256 + threadIdx.x;
  size_t base = ((size_t)b * L_ + lc * 256) * D_ + d;
  const float* xb = x + base;
  _Float16* x16b = reinterpret_cast<_Float16*>(ws + O_X16) + base;
  float acc = 0.f;
  for (int l = 0; l < 256; ++l) {
    float v = xb[(size_t)l * D_];
    acc += v * v;
    x16b[(size_t)l * D_] = (_Float16)v;
  }
  ws[O_SCP + ((size_t)b * 8 + lc) * D_ + d] = acc;
}

// cfb16[b,k,d] = fp16(200*log2e * cent[k,d] / max(scale[b,d]/L, eps))
// scale reduced inline from the 8 partials (16 KB per b -> L1-hot)
__global__ void k_cfb(const float* __restrict__ cent, float* ws) {
  int b = blockIdx.y;
  int f = (blockIdx.x * 256 + threadIdx.x) * 4;
  int d = f & (D_ - 1);
  float4 c = *reinterpret_cast<const float4*>(cent + f);
  float4 s4 = {0.f, 0.f, 0.f, 0.f};
  const float* scp = ws + O_SCP + (size_t)b * 8 * D_ + d;
#pragma unroll
  for (int lc = 0; lc < 8; ++lc) {
    float4 p = *reinterpret_cast<const float4*>(scp + lc * D_);
    s4.x += p.x; s4.y += p.y; s4.z += p.z; s4.w += p.w;
  }
  const float sc = 2.f * CONC_ * EXPSCALE;
  f16x4 h;
  h[0] = (_Float16)(c.x * sc / fmaxf(s4.x * (1.f / L_), EPS_));
  h[1] = (_Float16)(c.y * sc / fmaxf(s4.y * (1.f / L_), EPS_));
  h[2] = (_Float16)(c.z * sc / fmaxf(s4.z * (1.f / L_), EPS_));
  h[3] = (_Float16)(c.w * sc / fmaxf(s4.w * (1.f / L_), EPS_));
  *reinterpret_cast<f16x4*>(
      reinterpret_cast<_Float16*>(ws + O_CFB) + (size_t)b * K_ * D_ + f) = h;
}

// MFMA GEMM (log2-domain logits), single-buffered 128x128, BK=64 (r13-proven):
// 32 MFMA + 16 ds_read per 2 barriers. LDS rows 128 B, swizzle sw=slot^(row&7);
// staging dest linear, source inverse-swizzled. d-loop fully unrolled.
// Fused epilogue: chunk softmax partials (exp2) + P16 transposed [b][k][l].
// Grid 2048 1D, XCD-grouped: each XCD owns 4 b's (2.5 MB/b < 4 MB L2).
__global__ __launch_bounds__(256, 3) void k_gemm16(float* ws) {
  const int id = blockIdx.x;            // 0..2047
  const int xcd = id & 7;
  const int r = id >> 3;                // 0..255
  const int b = xcd + ((r >> 6) << 3);  // XCD owns b = xcd, xcd+8, +16, +24
  const int lk = r & 63;
  const int lchunk = lk & 15;
  const int l0 = lchunk * 128;
  const int k0 = (lk >> 4) * 128;

  __shared__ _Float16 As[128 * 64];   // 16 KB
  __shared__ _Float16 Bs[128 * 64];   // 16 KB
  const int tid = threadIdx.x;
  const int lane = tid & 63;
  const int w = tid >> 6;
  const int wm = w >> 1, wn = w & 1;

  const _Float16* xb16 = reinterpret_cast<const _Float16*>(ws + O_X16) +
                         (size_t)b * L_ * D_;
  const _Float16* cfb = reinterpret_cast<const _Float16*>(ws + O_CFB) +
                        (size_t)b * K_ * D_;

  f32x4 acc[4][4] = {};

#pragma unroll
  for (int d0 = 0; d0 < D_; d0 += 64) {
    // stage: 1024 16B-units per operand; dest linear, source inverse-swizzled
#pragma unroll
    for (int rr = 0; rr < 4; ++rr) {
      int u = rr * 256 + tid;              // unit 0..1023
      int row = u >> 3, j = u & 7;
      int sc = ((j ^ (row & 7)) << 3);     // halfs
      gl2lds16(xb16 + (size_t)(l0 + row) * D_ + d0 + sc, As + (size_t)u * 8);
    }
#pragma unroll
    for (int rr = 0; rr < 4; ++rr) {
      int u = rr * 256 + tid;
      int row = u >> 3, j = u & 7;
      int sc = ((j ^ (row & 7)) << 3);
      gl2lds16(cfb + (size_t)(k0 + row) * D_ + d0 + sc, Bs + (size_t)u * 8);
    }
    __syncthreads();

#pragma unroll
    for (int kk = 0; kk < 2; ++kk) {       // two K=32 halves of the BK=64 tile
      f16x8 af[4], bfr[4];
#pragma unroll
      for (int mi = 0; mi < 4; ++mi) {
        int row = wm * 64 + mi * 16 + (lane & 15);
        int slot = kk * 4 + (lane >> 4);
        int sw = slot ^ (row & 7);
        af[mi] = *reinterpret_cast<const f16x8*>(
            reinterpret_cast<const char*>(As) + row * 128 + sw * 16);
      }
#pragma unroll
      for (int ni = 0; ni < 4; ++ni) {
        int row = wn * 64 + ni * 16 + (lane & 15);
        int slot = kk * 4 + (lane >> 4);
        int sw = slot ^ (row & 7);
        bfr[ni] = *reinterpret_cast<const f16x8*>(
            reinterpret_cast<const char*>(Bs) + row * 128 + sw * 16);
      }
#pragma unroll
      for (int mi = 0; mi < 4; ++mi)
#pragma unroll
        for (int ni = 0; ni < 4; ++ni)
          acc[mi][ni] = __builtin_amdgcn_mfma_f32_16x16x32_f16(
              af[mi], bfr[ni], acc[mi][ni], 0, 0, 0);
    }
    __syncthreads();
  }

  // ---- fused softmax partials over this block's 128 l's (log2 domain) ----
  // (bias[k] omitted: constant over l, cancels in softmax over l)
  float* red = reinterpret_cast<float*>(As);   // [2 wm][128 k] wave maxes
  float* red2 = red + 256;                     // [2 wm][128 k] wave sums
  float pm[4], ps[4];
#pragma unroll
  for (int ni = 0; ni < 4; ++ni) {
    float m = -INFINITY;
#pragma unroll
    for (int mi = 0; mi < 4; ++mi)
#pragma unroll
      for (int j = 0; j < 4; ++j) m = fmaxf(m, acc[mi][ni][j]);
    m = fmaxf(m, __shfl_xor(m, 16));
    m = fmaxf(m, __shfl_xor(m, 32));
    pm[ni] = m;
  }
  if (lane < 16) {
#pragma unroll
    for (int ni = 0; ni < 4; ++ni)
      red[wm * 128 + wn * 64 + ni * 16 + lane] = pm[ni];
  }
  __syncthreads();
#pragma unroll
  for (int ni = 0; ni < 4; ++ni) {
    int idx = wn * 64 + ni * 16 + (lane & 15);
    pm[ni] = fmaxf(red[idx], red[128 + idx]);   // combined chunk max
  }
  // e = exp2(v' - m'); accumulate sum AND store P16 TRANSPOSED [b][k][l]
  _Float16* pg = reinterpret_cast<_Float16*>(ws + O_P16) + (size_t)b * K_ * L_;
#pragma unroll
  for (int ni = 0; ni < 4; ++ni) {
    int kc = k0 + wn * 64 + ni * 16 + (lane & 15);
    float s = 0.f;
#pragma unroll
    for (int mi = 0; mi < 4; ++mi) {
      int lr = l0 + wm * 64 + mi * 16 + (lane >> 4) * 4;
      f16x4 ev;
#pragma unroll
      for (int j = 0; j < 4; ++j) {
        float e = exp2f(acc[mi][ni][j] - pm[ni]);
        s += e;
        ev[j] = (_Float16)e;
      }
      *reinterpret_cast<f16x4*>(pg + (size_t)kc * L_ + lr) = ev;
    }
    s += __shfl_xor(s, 16);
    s += __shfl_xor(s, 32);
    ps[ni] = s;
  }
  if (lane < 16) {
#pragma unroll
    for (int ni = 0; ni < 4; ++ni)
      red2[wm * 128 + wn * 64 + ni * 16 + lane] = ps[ni];
  }
  __syncthreads();
  if (w < 2 && lane < 16) {
#pragma unroll
    for (int ni = 0; ni < 4; ++ni) {
      int idx = wn * 64 + ni * 16 + lane;
      float mg = fmaxf(red[idx], red[128 + idx]);
      float sg = red2[idx] + red2[128 + idx];
      size_t o = ((size_t)b * LSPLIT + lchunk) * K_ + k0 + idx;
      ws[O_PM + o] = mg;
      ws[O_PS + o] = sg;
    }
  }
}

// fused: combine chunk stats -> A[k] (exp2); w[l] = sum_k P16T[k,l]*A[k];
// wx partials -> wxp[b][ch][d] (plain store, no atomics)
__global__ __launch_bounds__(256) void k_wsumwx(float* ws) {
  int b = blockIdx.x, ch = blockIdx.y;
  int l0 = ch * 128;
  __shared__ float Al[512];
  __shared__ float wacc[16][128];
  __shared__ float wl[128];
  int tid = threadIdx.x;

  // combine: A[k] = exp2(pm[ch,k] - M[k]) / S[k]
  for (int kk = tid; kk < K_; kk += 256) {
    float pmv[LSPLIT], psv[LSPLIT];
    float M = -INFINITY;
#pragma unroll
    for (int c = 0; c < LSPLIT; ++c) {
      pmv[c] = ws[O_PM + ((size_t)b * LSPLIT + c) * K_ + kk];
      psv[c] = ws[O_PS + ((size_t)b * LSPLIT + c) * K_ + kk];
      M = fmaxf(M, pmv[c]);
    }
    float S = 0.f;
#pragma unroll
    for (int c = 0; c < LSPLIT; ++c) S += psv[c] * exp2f(pmv[c] - M);
    Al[kk] = exp2f(pmv[ch] - M) / S;
  }
  __syncthreads();

  // w-partials: thread = (kslice = tid>>4 : 32 k's, lpart = tid&15 : 8 l's)
  const _Float16* pt = reinterpret_cast<const _Float16*>(ws + O_P16) +
                       (size_t)b * K_ * L_ + l0;
  int lpart = tid & 15, kslice = tid >> 4;
  float a8[8] = {0.f, 0.f, 0.f, 0.f, 0.f, 0.f, 0.f, 0.f};
  for (int k = kslice * 32; k < kslice * 32 + 32; ++k) {
    float ak = Al[k];
    f16x8 v = *reinterpret_cast<const f16x8*>(pt + (size_t)k * L_ + lpart * 8);
#pragma unroll
    for (int i = 0; i < 8; ++i) a8[i] += ak * (float)v[i];
  }
#pragma unroll
  for (int i = 0; i < 8; ++i) wacc[kslice][lpart * 8 + i] = a8[i];
  __syncthreads();
  if (tid < 128) {
    float s = 0.f;
#pragma unroll
    for (int sl = 0; sl < 16; ++sl) s += wacc[sl][tid];
    wl[tid] = s;
  }
  __syncthreads();

  const _Float16* x16b = reinterpret_cast<const _Float16*>(ws + O_X16) +
                         (size_t)(b * L_ + l0) * D_;
  int half = tid >> 7;
  int dd = (tid & 127) * 4;
  float4 a4 = {0.f, 0.f, 0.f, 0.f};
  for (int l = half * 64; l < half * 64 + 64; ++l) {
    float wgt = wl[l];
    f16x4 xv = *reinterpret_cast<const f16x4*>(x16b + (size_t)l * D_ + dd);
    a4.x += wgt * (float)xv[0];
    a4.y += wgt * (float)xv[1];
    a4.z += wgt * (float)xv[2];
    a4.w += wgt * (float)xv[3];
  }
  // two half-l partials per chunk -> use per-half slots: index ch*2+half
  float* wxp = ws + O_WXP + ((size_t)b * 16 + ch) * D_ + dd;
  if (half == 0) {
    wxp[0] = a4.x; wxp[1] = a4.y; wxp[2] = a4.z; wxp[3] = a4.w;
  }
  __syncthreads();
  if (half == 1) {
    wxp[0] += a4.x; wxp[1] += a4.y; wxp[2] += a4.z; wxp[3] += a4.w;
  }
}

// out[b,d] = (scale/L) * (inv*wx/K - meanC[d]); partials reduced inline
__global__ void k_final(const float* ws, float* out) {
  int i = blockIdx.x * 256 + threadIdx.x;   // B*D
  int b = i >> 9, d = i & (D_ - 1);
  float scale = 0.f;
#pragma unroll
  for (int lc = 0; lc < 8; ++lc)
    scale += ws[O_SCP + ((size_t)b * 8 + lc) * D_ + d];
  float wx = 0.f;
#pragma unroll
  for (int c = 0; c < 16; ++c)
    wx += ws[O_WXP + ((size_t)b * 16 + c) * D_ + d];
  float sc = scale * (1.f / L_);
  float inv = 1.f / fmaxf(sc, EPS_);
  out[i] = sc * (inv * wx * (1.f / K_) - ws[O_MEANC + d]);
}

extern "C" void kernel_launch(void* const* d_in, const int* in_sizes, int n_in,
                              void* d_out, int out_size, void* d_ws, size_t ws_size,
                              hipStream_t stream) {
  const float* x = (const float*)d_in[0];
  const float* cent = (const float*)d_in[1];
  float* out = (float*)d_out;
  float* ws = (float*)d_ws;

  k_sqacc<<<dim3(B_, D_ / 256, 8), 256, 0, stream>>>(x, ws);
  k_meanc<<<2, 256, 0, stream>>>(cent, ws);
  k_cfb<<<dim3(K_ * D_ / 1024, B_), 256, 0, stream>>>(cent, ws);
  k_gemm16<<<2048, 256, 0, stream>>>(ws);
  k_wsumwx<<<dim3(B_, LSPLIT), 256, 0, stream>>>(ws);
  k_final<<<B_ * D_ / 256, 256, 0, stream>>>(ws, out);
}

// Round 15
// 131.174 us; speedup vs baseline: 1.3142x; 1.1280x over previous
//
#include <hip/hip_runtime.h>
#include <hip/hip_fp8.h>
#include <math.h>

#define B_ 32
#define L_ 2048
#define D_ 512
#define K_ 512
#define CONC_ 100.0f
#define EPS_ 1e-12f
#define LSPLIT 16            // 16 chunks of 128 l's (= GEMM l-tile)
#define EXPSCALE 1.44269504088896f   // log2(e); folded into cfb

typedef __attribute__((ext_vector_type(8))) _Float16 f16x8;
typedef __attribute__((ext_vector_type(4))) _Float16 f16x4;
typedef __attribute__((ext_vector_type(4))) float f32x4;

// ---- workspace layout (float offsets) ----
enum : size_t {
  O_MEANC = 0,                            // D
  O_PM    = O_MEANC + D_,                 // B*LSPLIT*K  chunk max (log2 units)
  O_PS    = O_PM + (size_t)B_*LSPLIT*K_,  // B*LSPLIT*K  chunk sum
  O_SCP   = O_PS + (size_t)B_*LSPLIT*K_,  // B*8*D   x^2 partials
  O_WXP   = O_SCP + (size_t)B_*8*D_,      // B*16*D  wx partials
  O_CFB   = O_WXP + (size_t)B_*16*D_,     // B*K*D halfs (200*log2e*cent*inv)
  O_X16   = O_CFB + (size_t)B_*K_*D_/2,   // B*L*D halfs (fp16 x)
  O_P8    = O_X16 + (size_t)B_*L_*D_/2,   // B*K*L BYTES, fp8 e4m3 exp2(v-m)
  WS_FLOATS = O_P8 + (size_t)B_*K_*L_/4
};

__device__ __forceinline__ void gl2lds16(const void* gsrc, void* lds) {
  __builtin_amdgcn_global_load_lds(
      (const __attribute__((address_space(1))) void*)gsrc,
      (__attribute__((address_space(3))) void*)lds, 16, 0, 0);
}

// x^2 partial sums (plain stores) AND x16 = fp16(x)
__global__ void k_sqacc(const float* __restrict__ x, float* ws) {
  int b = blockIdx.x, dc = blockIdx.y, lc = blockIdx.z;
  int d = dc * 256 + threadIdx.x;
  size_t base = ((size_t)b * L_ + lc * 256) * D_ + d;
  const float* xb = x + base;
  _Float16* x16b = reinterpret_cast<_Float16*>(ws + O_X16) + base;
  float acc = 0.f;
  for (int l = 0; l < 256; ++l) {
    float v = xb[(size_t)l * D_];
    acc += v * v;
    x16b[(size_t)l * D_] = (_Float16)v;
  }
  ws[O_SCP + ((size_t)b * 8 + lc) * D_ + d] = acc;
}

// merged: blocks 0..8191 -> cfb16[b,k,d]; blocks 8192..8193 -> meanC
__global__ void k_cfbm(const float* __restrict__ cent, float* ws) {
  int blk = blockIdx.x, tid = threadIdx.x;
  if (blk >= 8192) {
    int d = (blk - 8192) * 256 + tid;
    float s = 0.f;
    for (int k = 0; k < K_; ++k) s += cent[(size_t)k * D_ + d];
    ws[O_MEANC + d] = s * (1.f / K_);
    return;
  }
  int b = blk >> 8;
  int f = ((blk & 255) * 256 + tid) * 4;
  int d = f & (D_ - 1);
  float4 c = *reinterpret_cast<const float4*>(cent + f);
  float4 s4 = {0.f, 0.f, 0.f, 0.f};
  const float* scp = ws + O_SCP + (size_t)b * 8 * D_ + d;
#pragma unroll
  for (int lc = 0; lc < 8; ++lc) {
    float4 p = *reinterpret_cast<const float4*>(scp + lc * D_);
    s4.x += p.x; s4.y += p.y; s4.z += p.z; s4.w += p.w;
  }
  const float sc = 2.f * CONC_ * EXPSCALE;
  f16x4 h;
  h[0] = (_Float16)(c.x * sc / fmaxf(s4.x * (1.f / L_), EPS_));
  h[1] = (_Float16)(c.y * sc / fmaxf(s4.y * (1.f / L_), EPS_));
  h[2] = (_Float16)(c.z * sc / fmaxf(s4.z * (1.f / L_), EPS_));
  h[3] = (_Float16)(c.w * sc / fmaxf(s4.w * (1.f / L_), EPS_));
  *reinterpret_cast<f16x4*>(
      reinterpret_cast<_Float16*>(ws + O_CFB) + (size_t)b * K_ * D_ + f) = h;
}

// MFMA GEMM (log2-domain logits), single-buffered 128x128, BK=64 (r13/r14):
// 32 MFMA + 16 ds_read per 2 barriers; swizzle sw=slot^(row&7); d-loop
// fully unrolled. Fused epilogue: chunk softmax partials (exp2) + P stored
// fp8 e4m3 TRANSPOSED [b][k][l]. Grid 2048 1D, XCD-grouped (4 b's per XCD).
__global__ __launch_bounds__(256, 3) void k_gemm16(float* ws) {
  const int id = blockIdx.x;            // 0..2047
  const int xcd = id & 7;
  const int r = id >> 3;                // 0..255
  const int b = xcd + ((r >> 6) << 3);  // XCD owns b = xcd, xcd+8, +16, +24
  const int lk = r & 63;
  const int lchunk = lk & 15;
  const int l0 = lchunk * 128;
  const int k0 = (lk >> 4) * 128;

  __shared__ _Float16 As[128 * 64];   // 16 KB
  __shared__ _Float16 Bs[128 * 64];   // 16 KB
  const int tid = threadIdx.x;
  const int lane = tid & 63;
  const int w = tid >> 6;
  const int wm = w >> 1, wn = w & 1;

  const _Float16* xb16 = reinterpret_cast<const _Float16*>(ws + O_X16) +
                         (size_t)b * L_ * D_;
  const _Float16* cfb = reinterpret_cast<const _Float16*>(ws + O_CFB) +
                        (size_t)b * K_ * D_;

  f32x4 acc[4][4] = {};

#pragma unroll
  for (int d0 = 0; d0 < D_; d0 += 64) {
#pragma unroll
    for (int rr = 0; rr < 4; ++rr) {
      int u = rr * 256 + tid;              // unit 0..1023
      int row = u >> 3, j = u & 7;
      int sc = ((j ^ (row & 7)) << 3);     // halfs
      gl2lds16(xb16 + (size_t)(l0 + row) * D_ + d0 + sc, As + (size_t)u * 8);
    }
#pragma unroll
    for (int rr = 0; rr < 4; ++rr) {
      int u = rr * 256 + tid;
      int row = u >> 3, j = u & 7;
      int sc = ((j ^ (row & 7)) << 3);
      gl2lds16(cfb + (size_t)(k0 + row) * D_ + d0 + sc, Bs + (size_t)u * 8);
    }
    __syncthreads();

#pragma unroll
    for (int kk = 0; kk < 2; ++kk) {       // two K=32 halves of the BK=64 tile
      f16x8 af[4], bfr[4];
#pragma unroll
      for (int mi = 0; mi < 4; ++mi) {
        int row = wm * 64 + mi * 16 + (lane & 15);
        int slot = kk * 4 + (lane >> 4);
        int sw = slot ^ (row & 7);
        af[mi] = *reinterpret_cast<const f16x8*>(
            reinterpret_cast<const char*>(As) + row * 128 + sw * 16);
      }
#pragma unroll
      for (int ni = 0; ni < 4; ++ni) {
        int row = wn * 64 + ni * 16 + (lane & 15);
        int slot = kk * 4 + (lane >> 4);
        int sw = slot ^ (row & 7);
        bfr[ni] = *reinterpret_cast<const f16x8*>(
            reinterpret_cast<const char*>(Bs) + row * 128 + sw * 16);
      }
#pragma unroll
      for (int mi = 0; mi < 4; ++mi)
#pragma unroll
        for (int ni = 0; ni < 4; ++ni)
          acc[mi][ni] = __builtin_amdgcn_mfma_f32_16x16x32_f16(
              af[mi], bfr[ni], acc[mi][ni], 0, 0, 0);
    }
    __syncthreads();
  }

  // ---- fused softmax partials over this block's 128 l's (log2 domain) ----
  float* red = reinterpret_cast<float*>(As);   // [2 wm][128 k] wave maxes
  float* red2 = red + 256;                     // [2 wm][128 k] wave sums
  float pm[4], ps[4];
#pragma unroll
  for (int ni = 0; ni < 4; ++ni) {
    float m = -INFINITY;
#pragma unroll
    for (int mi = 0; mi < 4; ++mi)
#pragma unroll
      for (int j = 0; j < 4; ++j) m = fmaxf(m, acc[mi][ni][j]);
    m = fmaxf(m, __shfl_xor(m, 16));
    m = fmaxf(m, __shfl_xor(m, 32));
    pm[ni] = m;
  }
  if (lane < 16) {
#pragma unroll
    for (int ni = 0; ni < 4; ++ni)
      red[wm * 128 + wn * 64 + ni * 16 + lane] = pm[ni];
  }
  __syncthreads();
#pragma unroll
  for (int ni = 0; ni < 4; ++ni) {
    int idx = wn * 64 + ni * 16 + (lane & 15);
    pm[ni] = fmaxf(red[idx], red[128 + idx]);   // combined chunk max
  }
  // e = exp2(v' - m'); f32 sum for stats; store P fp8 TRANSPOSED [b][k][l]
  char* pg = reinterpret_cast<char*>(ws + O_P8) + (size_t)b * K_ * L_;
#pragma unroll
  for (int ni = 0; ni < 4; ++ni) {
    int kc = k0 + wn * 64 + ni * 16 + (lane & 15);
    float s = 0.f;
#pragma unroll
    for (int mi = 0; mi < 4; ++mi) {
      int lr = l0 + wm * 64 + mi * 16 + (lane >> 4) * 4;
      unsigned int pk = 0;
#pragma unroll
      for (int j = 0; j < 4; ++j) {
        float e = exp2f(acc[mi][ni][j] - pm[ni]);
        s += e;
        __hip_fp8_e4m3 q(e);
        pk |= (unsigned int)(q.__x) << (8 * j);
      }
      *reinterpret_cast<unsigned int*>(pg + (size_t)kc * L_ + lr) = pk;
    }
    s += __shfl_xor(s, 16);
    s += __shfl_xor(s, 32);
    ps[ni] = s;
  }
  if (lane < 16) {
#pragma unroll
    for (int ni = 0; ni < 4; ++ni)
      red2[wm * 128 + wn * 64 + ni * 16 + lane] = ps[ni];
  }
  __syncthreads();
  if (w < 2 && lane < 16) {
#pragma unroll
    for (int ni = 0; ni < 4; ++ni) {
      int idx = wn * 64 + ni * 16 + lane;
      float mg = fmaxf(red[idx], red[128 + idx]);
      float sg = red2[idx] + red2[128 + idx];
      size_t o = ((size_t)b * LSPLIT + lchunk) * K_ + k0 + idx;
      ws[O_PM + o] = mg;
      ws[O_PS + o] = sg;
    }
  }
}

// fused: combine chunk stats -> A[k] (exp2, f32); w[l] = sum_k P8[k,l]*A[k];
// wx partials -> wxp[b][ch][d] (plain store)
__global__ __launch_bounds__(256) void k_wsumwx(float* ws) {
  int b = blockIdx.x, ch = blockIdx.y;
  int l0 = ch * 128;
  __shared__ float Al[512];
  __shared__ float wacc[16][128];
  __shared__ float wl[128];
  int tid = threadIdx.x;

  for (int kk = tid; kk < K_; kk += 256) {
    float pmv[LSPLIT], psv[LSPLIT];
    float M = -INFINITY;
#pragma unroll
    for (int c = 0; c < LSPLIT; ++c) {
      pmv[c] = ws[O_PM + ((size_t)b * LSPLIT + c) * K_ + kk];
      psv[c] = ws[O_PS + ((size_t)b * LSPLIT + c) * K_ + kk];
      M = fmaxf(M, pmv[c]);
    }
    float S = 0.f;
#pragma unroll
    for (int c = 0; c < LSPLIT; ++c) S += psv[c] * exp2f(pmv[c] - M);
    Al[kk] = exp2f(pmv[ch] - M) / S;
  }
  __syncthreads();

  // w-partials: thread = (kslice = tid>>4 : 32 k's, lpart = tid&15 : 8 l's)
  const char* pt = reinterpret_cast<const char*>(ws + O_P8) +
                   (size_t)b * K_ * L_ + l0;
  int lpart = tid & 15, kslice = tid >> 4;
  float a8[8] = {0.f, 0.f, 0.f, 0.f, 0.f, 0.f, 0.f, 0.f};
  for (int k = kslice * 32; k < kslice * 32 + 32; ++k) {
    float ak = Al[k];
    uint2 v = *reinterpret_cast<const uint2*>(pt + (size_t)k * L_ + lpart * 8);
#pragma unroll
    for (int i = 0; i < 4; ++i) {
      __hip_fp8_e4m3 q;
      q.__x = (__hip_fp8_storage_t)((v.x >> (8 * i)) & 0xff);
      a8[i] += ak * (float)q;
    }
#pragma unroll
    for (int i = 0; i < 4; ++i) {
      __hip_fp8_e4m3 q;
      q.__x = (__hip_fp8_storage_t)((v.y >> (8 * i)) & 0xff);
      a8[4 + i] += ak * (float)q;
    }
  }
#pragma unroll
  for (int i = 0; i < 8; ++i) wacc[kslice][lpart * 8 + i] = a8[i];
  __syncthreads();
  if (tid < 128) {
    float s = 0.f;
#pragma unroll
    for (int sl = 0; sl < 16; ++sl) s += wacc[sl][tid];
    wl[tid] = s;
  }
  __syncthreads();

  const _Float16* x16b = reinterpret_cast<const _Float16*>(ws + O_X16) +
                         (size_t)(b * L_ + l0) * D_;
  int half = tid >> 7;
  int dd = (tid & 127) * 4;
  float4 a4 = {0.f, 0.f, 0.f, 0.f};
  for (int l = half * 64; l < half * 64 + 64; ++l) {
    float wgt = wl[l];
    f16x4 xv = *reinterpret_cast<const f16x4*>(x16b + (size_t)l * D_ + dd);
    a4.x += wgt * (float)xv[0];
    a4.y += wgt * (float)xv[1];
    a4.z += wgt * (float)xv[2];
    a4.w += wgt * (float)xv[3];
  }
  float* wxp = ws + O_WXP + ((size_t)b * 16 + ch) * D_ + dd;
  if (half == 0) {
    wxp[0] = a4.x; wxp[1] = a4.y; wxp[2] = a4.z; wxp[3] = a4.w;
  }
  __syncthreads();
  if (half == 1) {
    wxp[0] += a4.x; wxp[1] += a4.y; wxp[2] += a4.z; wxp[3] += a4.w;
  }
}

// out[b,d] = (scale/L) * (inv*wx/K - meanC[d]); partials reduced inline
__global__ void k_final(const float* ws, float* out) {
  int i = blockIdx.x * 256 + threadIdx.x;   // B*D
  int b = i >> 9, d = i & (D_ - 1);
  float scale = 0.f;
#pragma unroll
  for (int lc = 0; lc < 8; ++lc)
    scale += ws[O_SCP + ((size_t)b * 8 + lc) * D_ + d];
  float wx = 0.f;
#pragma unroll
  for (int c = 0; c < 16; ++c)
    wx += ws[O_WXP + ((size_t)b * 16 + c) * D_ + d];
  float sc = scale * (1.f / L_);
  float inv = 1.f / fmaxf(sc, EPS_);
  out[i] = sc * (inv * wx * (1.f / K_) - ws[O_MEANC + d]);
}

extern "C" void kernel_launch(void* const* d_in, const int* in_sizes, int n_in,
                              void* d_out, int out_size, void* d_ws, size_t ws_size,
                              hipStream_t stream) {
  const float* x = (const float*)d_in[0];
  const float* cent = (const float*)d_in[1];
  float* out = (float*)d_out;
  float* ws = (float*)d_ws;

  k_sqacc<<<dim3(B_, D_ / 256, 8), 256, 0, stream>>>(x, ws);
  k_cfbm<<<8194, 256, 0, stream>>>(cent, ws);
  k_gemm16<<<2048, 256, 0, stream>>>(ws);
  k_wsumwx<<<dim3(B_, LSPLIT), 256, 0, stream>>>(ws);
  k_final<<<B_ * D_ / 256, 256, 0, stream>>>(ws, out);
}

// Round 16
// 130.006 us; speedup vs baseline: 1.3260x; 1.0090x over previous
//
#include <hip/hip_runtime.h>
#include <hip/hip_fp8.h>
#include <math.h>

#define B_ 32
#define L_ 2048
#define D_ 512
#define K_ 512
#define CONC_ 100.0f
#define EPS_ 1e-12f
#define LSPLIT 16            // 16 chunks of 128 l's (= GEMM l-tile)
#define EXPSCALE 1.44269504088896f   // log2(e); folded into cfb

typedef __attribute__((ext_vector_type(8))) _Float16 f16x8;
typedef __attribute__((ext_vector_type(4))) _Float16 f16x4;
typedef __attribute__((ext_vector_type(4))) float f32x4;

// ---- workspace layout (float offsets) ----
enum : size_t {
  O_MEANC = 0,                            // D
  O_PM    = O_MEANC + D_,                 // B*LSPLIT*K  chunk max (log2 units)
  O_PS    = O_PM + (size_t)B_*LSPLIT*K_,  // B*LSPLIT*K  chunk sum
  O_SCP   = O_PS + (size_t)B_*LSPLIT*K_,  // B*8*D   x^2 partials
  O_WXP   = O_SCP + (size_t)B_*8*D_,      // B*16*D  wx partials
  O_CFB   = O_WXP + (size_t)B_*16*D_,     // B*K*D halfs (200*log2e*cent*inv)
  O_X16   = O_CFB + (size_t)B_*K_*D_/2,   // B*L*D halfs (fp16 x)
  O_P8    = O_X16 + (size_t)B_*L_*D_/2,   // B*K*L BYTES, fp8 e4m3 exp2(v-m)
  WS_FLOATS = O_P8 + (size_t)B_*K_*L_/4
};

__device__ __forceinline__ void gl2lds16(const void* gsrc, void* lds) {
  __builtin_amdgcn_global_load_lds(
      (const __attribute__((address_space(1))) void*)gsrc,
      (__attribute__((address_space(3))) void*)lds, 16, 0, 0);
}

// x^2 partial sums AND x16 = fp16(x) — vectorized float4/f16x4 (G13).
// 512 threads: d4 = (tid&127)*4, quarter h = tid>>7 (64 l's each);
// 4 quarters LDS-combined -> single (b,lc) partial (keeps 8 partials/b).
__global__ __launch_bounds__(512) void k_sqacc(const float* __restrict__ x,
                                               float* ws) {
  int b = blockIdx.x, lc = blockIdx.y;      // lc 0..7 -> 256 l's
  int tid = threadIdx.x;
  int d4 = (tid & 127) << 2;
  int h = tid >> 7;                          // 0..3
  __shared__ float sacc[4][512];
  size_t base = ((size_t)b * L_ + lc * 256 + h * 64) * D_ + d4;
  const float* xb = x + base;
  _Float16* x16b = reinterpret_cast<_Float16*>(ws + O_X16) + base;
  float a0 = 0.f, a1 = 0.f, a2 = 0.f, a3 = 0.f;
  for (int l = 0; l < 64; ++l) {
    float4 v = *reinterpret_cast<const float4*>(xb + (size_t)l * D_);
    a0 += v.x * v.x; a1 += v.y * v.y; a2 += v.z * v.z; a3 += v.w * v.w;
    f16x4 hv;
    hv[0] = (_Float16)v.x; hv[1] = (_Float16)v.y;
    hv[2] = (_Float16)v.z; hv[3] = (_Float16)v.w;
    *reinterpret_cast<f16x4*>(x16b + (size_t)l * D_) = hv;
  }
  sacc[h][d4 + 0] = a0; sacc[h][d4 + 1] = a1;
  sacc[h][d4 + 2] = a2; sacc[h][d4 + 3] = a3;
  __syncthreads();
  if (h == 0) {
    float4 r;
    r.x = sacc[0][d4 + 0] + sacc[1][d4 + 0] + sacc[2][d4 + 0] + sacc[3][d4 + 0];
    r.y = sacc[0][d4 + 1] + sacc[1][d4 + 1] + sacc[2][d4 + 1] + sacc[3][d4 + 1];
    r.z = sacc[0][d4 + 2] + sacc[1][d4 + 2] + sacc[2][d4 + 2] + sacc[3][d4 + 2];
    r.w = sacc[0][d4 + 3] + sacc[1][d4 + 3] + sacc[2][d4 + 3] + sacc[3][d4 + 3];
    *reinterpret_cast<float4*>(ws + O_SCP + ((size_t)b * 8 + lc) * D_ + d4) = r;
  }
}

// merged: blocks 0..8191 -> cfb16[b,k,d]; blocks 8192..8193 -> meanC
__global__ void k_cfbm(const float* __restrict__ cent, float* ws) {
  int blk = blockIdx.x, tid = threadIdx.x;
  if (blk >= 8192) {
    int d = (blk - 8192) * 256 + tid;
    float s = 0.f;
    for (int k = 0; k < K_; ++k) s += cent[(size_t)k * D_ + d];
    ws[O_MEANC + d] = s * (1.f / K_);
    return;
  }
  int b = blk >> 8;
  int f = ((blk & 255) * 256 + tid) * 4;
  int d = f & (D_ - 1);
  float4 c = *reinterpret_cast<const float4*>(cent + f);
  float4 s4 = {0.f, 0.f, 0.f, 0.f};
  const float* scp = ws + O_SCP + (size_t)b * 8 * D_ + d;
#pragma unroll
  for (int lc = 0; lc < 8; ++lc) {
    float4 p = *reinterpret_cast<const float4*>(scp + lc * D_);
    s4.x += p.x; s4.y += p.y; s4.z += p.z; s4.w += p.w;
  }
  const float sc = 2.f * CONC_ * EXPSCALE;
  f16x4 h;
  h[0] = (_Float16)(c.x * sc / fmaxf(s4.x * (1.f / L_), EPS_));
  h[1] = (_Float16)(c.y * sc / fmaxf(s4.y * (1.f / L_), EPS_));
  h[2] = (_Float16)(c.z * sc / fmaxf(s4.z * (1.f / L_), EPS_));
  h[3] = (_Float16)(c.w * sc / fmaxf(s4.w * (1.f / L_), EPS_));
  *reinterpret_cast<f16x4*>(
      reinterpret_cast<_Float16*>(ws + O_CFB) + (size_t)b * K_ * D_ + f) = h;
}

// MFMA GEMM (log2-domain logits), single-buffered 128x128, BK=64:
// 32 MFMA + 16 ds_read per 2 barriers; swizzle sw=slot^(row&7); d-loop
// fully unrolled. launch_bounds(256,4): cap 128 VGPR -> 4 blocks/CU TLP.
// Fused epilogue: chunk softmax partials (exp2) + P fp8 e4m3 [b][k][l].
// Grid 2048 1D, XCD-grouped (4 b's per XCD -> cfb/x16 L2-resident).
__global__ __launch_bounds__(256, 4) void k_gemm16(float* ws) {
  const int id = blockIdx.x;            // 0..2047
  const int xcd = id & 7;
  const int r = id >> 3;                // 0..255
  const int b = xcd + ((r >> 6) << 3);  // XCD owns b = xcd, xcd+8, +16, +24
  const int lk = r & 63;
  const int lchunk = lk & 15;
  const int l0 = lchunk * 128;
  const int k0 = (lk >> 4) * 128;

  __shared__ _Float16 As[128 * 64];   // 16 KB
  __shared__ _Float16 Bs[128 * 64];   // 16 KB
  const int tid = threadIdx.x;
  const int lane = tid & 63;
  const int w = tid >> 6;
  const int wm = w >> 1, wn = w & 1;

  const _Float16* xb16 = reinterpret_cast<const _Float16*>(ws + O_X16) +
                         (size_t)b * L_ * D_;
  const _Float16* cfb = reinterpret_cast<const _Float16*>(ws + O_CFB) +
                        (size_t)b * K_ * D_;

  f32x4 acc[4][4] = {};

#pragma unroll
  for (int d0 = 0; d0 < D_; d0 += 64) {
#pragma unroll
    for (int rr = 0; rr < 4; ++rr) {
      int u = rr * 256 + tid;              // unit 0..1023
      int row = u >> 3, j = u & 7;
      int sc = ((j ^ (row & 7)) << 3);     // halfs
      gl2lds16(xb16 + (size_t)(l0 + row) * D_ + d0 + sc, As + (size_t)u * 8);
    }
#pragma unroll
    for (int rr = 0; rr < 4; ++rr) {
      int u = rr * 256 + tid;
      int row = u >> 3, j = u & 7;
      int sc = ((j ^ (row & 7)) << 3);
      gl2lds16(cfb + (size_t)(k0 + row) * D_ + d0 + sc, Bs + (size_t)u * 8);
    }
    __syncthreads();

#pragma unroll
    for (int kk = 0; kk < 2; ++kk) {       // two K=32 halves of the BK=64 tile
      f16x8 af[4], bfr[4];
#pragma unroll
      for (int mi = 0; mi < 4; ++mi) {
        int row = wm * 64 + mi * 16 + (lane & 15);
        int slot = kk * 4 + (lane >> 4);
        int sw = slot ^ (row & 7);
        af[mi] = *reinterpret_cast<const f16x8*>(
            reinterpret_cast<const char*>(As) + row * 128 + sw * 16);
      }
#pragma unroll
      for (int ni = 0; ni < 4; ++ni) {
        int row = wn * 64 + ni * 16 + (lane & 15);
        int slot = kk * 4 + (lane >> 4);
        int sw = slot ^ (row & 7);
        bfr[ni] = *reinterpret_cast<const f16x8*>(
            reinterpret_cast<const char*>(Bs) + row * 128 + sw * 16);
      }
#pragma unroll
      for (int mi = 0; mi < 4; ++mi)
#pragma unroll
        for (int ni = 0; ni < 4; ++ni)
          acc[mi][ni] = __builtin_amdgcn_mfma_f32_16x16x32_f16(
              af[mi], bfr[ni], acc[mi][ni], 0, 0, 0);
    }
    __syncthreads();
  }

  // ---- fused softmax partials over this block's 128 l's (log2 domain) ----
  float* red = reinterpret_cast<float*>(As);   // [2 wm][128 k] wave maxes
  float* red2 = red + 256;                     // [2 wm][128 k] wave sums
  float pm[4], ps[4];
#pragma unroll
  for (int ni = 0; ni < 4; ++ni) {
    float m = -INFINITY;
#pragma unroll
    for (int mi = 0; mi < 4; ++mi)
#pragma unroll
      for (int j = 0; j < 4; ++j) m = fmaxf(m, acc[mi][ni][j]);
    m = fmaxf(m, __shfl_xor(m, 16));
    m = fmaxf(m, __shfl_xor(m, 32));
    pm[ni] = m;
  }
  if (lane < 16) {
#pragma unroll
    for (int ni = 0; ni < 4; ++ni)
      red[wm * 128 + wn * 64 + ni * 16 + lane] = pm[ni];
  }
  __syncthreads();
#pragma unroll
  for (int ni = 0; ni < 4; ++ni) {
    int idx = wn * 64 + ni * 16 + (lane & 15);
    pm[ni] = fmaxf(red[idx], red[128 + idx]);   // combined chunk max
  }
  // e = exp2(v' - m'); f32 sum for stats; store P fp8 TRANSPOSED [b][k][l]
  char* pg = reinterpret_cast<char*>(ws + O_P8) + (size_t)b * K_ * L_;
#pragma unroll
  for (int ni = 0; ni < 4; ++ni) {
    int kc = k0 + wn * 64 + ni * 16 + (lane & 15);
    float s = 0.f;
#pragma unroll
    for (int mi = 0; mi < 4; ++mi) {
      int lr = l0 + wm * 64 + mi * 16 + (lane >> 4) * 4;
      unsigned int pk = 0;
#pragma unroll
      for (int j = 0; j < 4; ++j) {
        float e = exp2f(acc[mi][ni][j] - pm[ni]);
        s += e;
        __hip_fp8_e4m3 q(e);
        pk |= (unsigned int)(q.__x) << (8 * j);
      }
      *reinterpret_cast<unsigned int*>(pg + (size_t)kc * L_ + lr) = pk;
    }
    s += __shfl_xor(s, 16);
    s += __shfl_xor(s, 32);
    ps[ni] = s;
  }
  if (lane < 16) {
#pragma unroll
    for (int ni = 0; ni < 4; ++ni)
      red2[wm * 128 + wn * 64 + ni * 16 + lane] = ps[ni];
  }
  __syncthreads();
  if (w < 2 && lane < 16) {
#pragma unroll
    for (int ni = 0; ni < 4; ++ni) {
      int idx = wn * 64 + ni * 16 + lane;
      float mg = fmaxf(red[idx], red[128 + idx]);
      float sg = red2[idx] + red2[128 + idx];
      size_t o = ((size_t)b * LSPLIT + lchunk) * K_ + k0 + idx;
      ws[O_PM + o] = mg;
      ws[O_PS + o] = sg;
    }
  }
}

// fused: combine chunk stats -> A[k] (exp2, f32); w[l] = sum_k P8[k,l]*A[k];
// wx partials -> wxp[b][ch][d] (plain store)
__global__ __launch_bounds__(256) void k_wsumwx(float* ws) {
  int b = blockIdx.x, ch = blockIdx.y;
  int l0 = ch * 128;
  __shared__ float Al[512];
  __shared__ float wacc[16][128];
  __shared__ float wl[128];
  int tid = threadIdx.x;

  for (int kk = tid; kk < K_; kk += 256) {
    float pmv[LSPLIT], psv[LSPLIT];
    float M = -INFINITY;
#pragma unroll
    for (int c = 0; c < LSPLIT; ++c) {
      pmv[c] = ws[O_PM + ((size_t)b * LSPLIT + c) * K_ + kk];
      psv[c] = ws[O_PS + ((size_t)b * LSPLIT + c) * K_ + kk];
      M = fmaxf(M, pmv[c]);
    }
    float S = 0.f;
#pragma unroll
    for (int c = 0; c < LSPLIT; ++c) S += psv[c] * exp2f(pmv[c] - M);
    Al[kk] = exp2f(pmv[ch] - M) / S;
  }
  __syncthreads();

  // w-partials: thread = (kslice = tid>>4 : 32 k's, lpart = tid&15 : 8 l's)
  const char* pt = reinterpret_cast<const char*>(ws + O_P8) +
                   (size_t)b * K_ * L_ + l0;
  int lpart = tid & 15, kslice = tid >> 4;
  float a8[8] = {0.f, 0.f, 0.f, 0.f, 0.f, 0.f, 0.f, 0.f};
  for (int k = kslice * 32; k < kslice * 32 + 32; ++k) {
    float ak = Al[k];
    uint2 v = *reinterpret_cast<const uint2*>(pt + (size_t)k * L_ + lpart * 8);
#pragma unroll
    for (int i = 0; i < 4; ++i) {
      __hip_fp8_e4m3 q;
      q.__x = (__hip_fp8_storage_t)((v.x >> (8 * i)) & 0xff);
      a8[i] += ak * (float)q;
    }
#pragma unroll
    for (int i = 0; i < 4; ++i) {
      __hip_fp8_e4m3 q;
      q.__x = (__hip_fp8_storage_t)((v.y >> (8 * i)) & 0xff);
      a8[4 + i] += ak * (float)q;
    }
  }
#pragma unroll
  for (int i = 0; i < 8; ++i) wacc[kslice][lpart * 8 + i] = a8[i];
  __syncthreads();
  if (tid < 128) {
    float s = 0.f;
#pragma unroll
    for (int sl = 0; sl < 16; ++sl) s += wacc[sl][tid];
    wl[tid] = s;
  }
  __syncthreads();

  const _Float16* x16b = reinterpret_cast<const _Float16*>(ws + O_X16) +
                         (size_t)(b * L_ + l0) * D_;
  int half = tid >> 7;
  int dd = (tid & 127) * 4;
  float4 a4 = {0.f, 0.f, 0.f, 0.f};
  for (int l = half * 64; l < half * 64 + 64; ++l) {
    float wgt = wl[l];
    f16x4 xv = *reinterpret_cast<const f16x4*>(x16b + (size_t)l * D_ + dd);
    a4.x += wgt * (float)xv[0];
    a4.y += wgt * (float)xv[1];
    a4.z += wgt * (float)xv[2];
    a4.w += wgt * (float)xv[3];
  }
  float* wxp = ws + O_WXP + ((size_t)b * 16 + ch) * D_ + dd;
  if (half == 0) {
    wxp[0] = a4.x; wxp[1] = a4.y; wxp[2] = a4.z; wxp[3] = a4.w;
  }
  __syncthreads();
  if (half == 1) {
    wxp[0] += a4.x; wxp[1] += a4.y; wxp[2] += a4.z; wxp[3] += a4.w;
  }
}

// out[b,d] = (scale/L) * (inv*wx/K - meanC[d]); partials reduced inline
__global__ void k_final(const float* ws, float* out) {
  int i = blockIdx.x * 256 + threadIdx.x;   // B*D
  int b = i >> 9, d = i & (D_ - 1);
  float scale = 0.f;
#pragma unroll
  for (int lc = 0; lc < 8; ++lc)
    scale += ws[O_SCP + ((size_t)b * 8 + lc) * D_ + d];
  float wx = 0.f;
#pragma unroll
  for (int c = 0; c < 16; ++c)
    wx += ws[O_WXP + ((size_t)b * 16 + c) * D_ + d];
  float sc = scale * (1.f / L_);
  float inv = 1.f / fmaxf(sc, EPS_);
  out[i] = sc * (inv * wx * (1.f / K_) - ws[O_MEANC + d]);
}

extern "C" void kernel_launch(void* const* d_in, const int* in_sizes, int n_in,
                              void* d_out, int out_size, void* d_ws, size_t ws_size,
                              hipStream_t stream) {
  const float* x = (const float*)d_in[0];
  const float* cent = (const float*)d_in[1];
  float* out = (float*)d_out;
  float* ws = (float*)d_ws;

  k_sqacc<<<dim3(B_, 8), 512, 0, stream>>>(x, ws);
  k_cfbm<<<8194, 256, 0, stream>>>(cent, ws);
  k_gemm16<<<2048, 256, 0, stream>>>(ws);
  k_wsumwx<<<dim3(B_, LSPLIT), 256, 0, stream>>>(ws);
  k_final<<<B_ * D_ / 256, 256, 0, stream>>>(ws, out);
}